// Round 1
// baseline (1782.058 us; speedup 1.0000x reference)
//
#include <hip/hip_runtime.h>

#define T_STEPS 256
#define B_ROWS  1024
#define NX_ 256
#define NY_ 64
#define NU_ 64
#define ND_ 32

#define CHUNK   32
#define NCHUNK  8          // T_STEPS / CHUNK

typedef _Float16 half8 __attribute__((ext_vector_type(8)));
typedef float    f32x4 __attribute__((ext_vector_type(4)));

#define MFMA16(a,b,c) __builtin_amdgcn_mfma_f32_16x16x32_f16((a),(b),(c),0,0,0)

#define XPITCH 264              // padded LDS row pitch (halfs): 2-way max on b128
#define XBUFSZ (16*XPITCH)

// Barrier that drains ONLY LDS (lgkmcnt) — global stores / prefetch loads stay
// in flight across it. The only cross-wave hazard per step is the LDS x-buffer.
// asm memory clobbers on both sides stop the compiler from moving LDS ops
// across the raw s_barrier.
__device__ __forceinline__ void block_sync_lds() {
  asm volatile("s_waitcnt lgkmcnt(0)" ::: "memory");
  __builtin_amdgcn_s_barrier();
  asm volatile("" ::: "memory");
}

__device__ __forceinline__ half8 cvt8(f32x4 a, f32x4 b) {
  half8 h;
  h[0]=(_Float16)a[0]; h[1]=(_Float16)a[1]; h[2]=(_Float16)a[2]; h[3]=(_Float16)a[3];
  h[4]=(_Float16)b[0]; h[5]=(_Float16)b[1]; h[6]=(_Float16)b[2]; h[7]=(_Float16)b[3];
  return h;
}

// ---------------------------------------------------------------------------
// out = in @ in (256x256 f32). from_wx: in-matrix is M = Wx^T read from Wx.
// M[r][k] = Wx[k][r]. One block per output row, one thread per column.
// ---------------------------------------------------------------------------
extern "C" __global__ __launch_bounds__(256)
void matsq(const float* __restrict__ src, float* __restrict__ dst, int from_wx)
{
  const int r = blockIdx.x, c = threadIdx.x;
  float acc = 0.f;
  if (from_wx) {
    for (int k = 0; k < NX_; k++) acc += src[k*NX_ + r] * src[c*NX_ + k];
  } else {
    for (int k = 0; k < NX_; k++) acc += src[r*NX_ + k] * src[k*NX_ + c];
  }
  dst[r*NX_ + c] = acc;
}

// ---------------------------------------------------------------------------
// Phase 1: per (row-group, chunk) scan from zero state (chunk 0: from x0).
// Stores only the chunk-final state (f32) to Lend[chunk][B][NX].
// ---------------------------------------------------------------------------
extern "C" __global__ __launch_bounds__(512, 4)
void phase1(const float* __restrict__ x0,
            const float* __restrict__ U,
            const float* __restrict__ Dd,
            const float* __restrict__ Wx,
            const float* __restrict__ bx,
            const float* __restrict__ Wu,
            const float* __restrict__ bu,
            const float* __restrict__ Wd,
            const float* __restrict__ bd,
            float* __restrict__ Lend)
{
  __shared__ __align__(16) _Float16 xb[2*XBUFSZ];

  const int tid  = threadIdx.x;
  const int lane = tid & 63;
  const int w    = tid >> 6;
  const int q    = lane >> 4;
  const int n16  = lane & 15;
  const int b0   = blockIdx.x * 16;
  const int ck   = blockIdx.y;          // chunk 0..6
  const int t0   = ck * CHUNK;
  const int c0   = w * 32;

  // ---- stage init state into xb[0] ----
  if (ck == 0) {
    int row = tid >> 5, ch = tid & 31;
    const float* s = x0 + (size_t)(b0+row)*NX_ + ch*8;
    _Float16* dst = &xb[row*XPITCH + ch*8];
    #pragma unroll
    for (int j=0;j<8;j++) dst[j] = (_Float16)s[j];
  } else {
    for (int i = tid; i < XBUFSZ; i += 512) xb[i] = (_Float16)0.f;
  }

  // ---- Wx hi/lo B-frags ----
  half8 Wh[2][8], Wl[2][8];
  #pragma unroll
  for (int nt=0; nt<2; nt++) {
    const int row = c0 + nt*16 + n16;
    #pragma unroll
    for (int kk=0; kk<8; kk++) {
      const float* s = Wx + row*NX_ + kk*32 + q*8;
      half8 h, l;
      #pragma unroll
      for (int j=0;j<8;j++){
        float v = s[j];
        _Float16 hi = (_Float16)v;
        h[j] = hi;
        l[j] = (_Float16)(v - (float)hi);
      }
      Wh[nt][kk]=h; Wl[nt][kk]=l;
    }
  }
  half8 WuF[2][2];
  #pragma unroll
  for (int nt=0;nt<2;nt++){
    const int row=c0+nt*16+n16;
    #pragma unroll
    for(int kk=0;kk<2;kk++){
      const float* s=Wu+row*NU_+kk*32+q*8; half8 h;
      #pragma unroll
      for(int j=0;j<8;j++) h[j]=(_Float16)s[j];
      WuF[nt][kk]=h;
    }
  }
  half8 WdF[2];
  #pragma unroll
  for(int nt=0;nt<2;nt++){
    const int row=c0+nt*16+n16;
    const float* s=Wd+row*ND_+q*8; half8 h;
    #pragma unroll
    for(int j=0;j<8;j++) h[j]=(_Float16)s[j];
    WdF[nt]=h;
  }
  const float bxs[2] = { bx[c0+n16], bx[c0+16+n16] };
  const float bus[2] = { bu[c0+n16], bu[c0+16+n16] };
  const float bds[2] = { bd[c0+n16], bd[c0+16+n16] };

  float xcv[2][4];
  #pragma unroll
  for(int nt=0;nt<2;nt++)
    #pragma unroll
    for(int r=0;r<4;r++)
      xcv[nt][r] = (ck==0) ? x0[(size_t)(b0+q*4+r)*NX_ + c0+nt*16+n16] : 0.f;

  // ---- prologue: preload u/d for t0 (stays in flight across the barrier) ----
  f32x4 u0a,u0b,u1a,u1b,d0a,d0b;
  {
    const float* usrc = U  + ((size_t)t0*B_ROWS + b0 + n16)*NU_;
    const float* dsrc = Dd + ((size_t)t0*B_ROWS + b0 + n16)*ND_;
    u0a = *(const f32x4*)(usrc + q*8);
    u0b = *(const f32x4*)(usrc + q*8 + 4);
    u1a = *(const f32x4*)(usrc + 32 + q*8);
    u1b = *(const f32x4*)(usrc + 32 + q*8 + 4);
    d0a = *(const f32x4*)(dsrc + q*8);
    d0b = *(const f32x4*)(dsrc + q*8 + 4);
  }

  block_sync_lds();

  for (int tt=0; tt<CHUNK; tt++) {
    const _Float16* xr = xb + (tt&1)*XBUFSZ;
    _Float16*       xw = xb + ((tt&1)^1)*XBUFSZ;

    f32x4 xn[2];
    xn[0] = (f32x4){bxs[0],bxs[0],bxs[0],bxs[0]};
    xn[1] = (f32x4){bxs[1],bxs[1],bxs[1],bxs[1]};
    #pragma unroll
    for (int kk=0;kk<8;kk++){
      half8 xa = *(const half8*)(xr + n16*XPITCH + kk*32 + q*8);
      xn[0] = MFMA16(xa, Wh[0][kk], xn[0]);
      xn[1] = MFMA16(xa, Wh[1][kk], xn[1]);
      xn[0] = MFMA16(xa, Wl[0][kk], xn[0]);
      xn[1] = MFMA16(xa, Wl[1][kk], xn[1]);
    }

    half8 uf0 = cvt8(u0a,u0b), uf1 = cvt8(u1a,u1b), df = cvt8(d0a,d0b);

    // ---- prefetch u/d for t+1 (WAR on regs just consumed by cvt8) ----
    {
      const int tn = t0 + ((tt+1 < CHUNK) ? tt+1 : tt);
      const float* un = U  + ((size_t)tn*B_ROWS + b0 + n16)*NU_;
      const float* dn = Dd + ((size_t)tn*B_ROWS + b0 + n16)*ND_;
      u0a = *(const f32x4*)(un + q*8);
      u0b = *(const f32x4*)(un + q*8 + 4);
      u1a = *(const f32x4*)(un + 32 + q*8);
      u1b = *(const f32x4*)(un + 32 + q*8 + 4);
      d0a = *(const f32x4*)(dn + q*8);
      d0b = *(const f32x4*)(dn + q*8 + 4);
    }

    f32x4 fu[2], fd[2];
    fu[0] = (f32x4){bus[0],bus[0],bus[0],bus[0]};
    fu[1] = (f32x4){bus[1],bus[1],bus[1],bus[1]};
    fd[0] = (f32x4){bds[0],bds[0],bds[0],bds[0]};
    fd[1] = (f32x4){bds[1],bds[1],bds[1],bds[1]};
    fu[0] = MFMA16(uf0, WuF[0][0], fu[0]);  fu[0] = MFMA16(uf1, WuF[0][1], fu[0]);
    fu[1] = MFMA16(uf0, WuF[1][0], fu[1]);  fu[1] = MFMA16(uf1, WuF[1][1], fu[1]);
    fd[0] = MFMA16(df,  WdF[0],    fd[0]);
    fd[1] = MFMA16(df,  WdF[1],    fd[1]);

    #pragma unroll
    for (int nt=0;nt<2;nt++){
      #pragma unroll
      for (int r=0;r<4;r++){
        float z = xn[nt][r] + fu[nt][r] + fd[nt][r];
        xw[(q*4+r)*XPITCH + c0+nt*16+n16] = (_Float16)z;
        xcv[nt][r] = z;
      }
    }
    block_sync_lds();
  }

  // store chunk-final state
  float* dst = Lend + (size_t)ck*(B_ROWS*NX_);
  #pragma unroll
  for (int nt=0;nt<2;nt++)
    #pragma unroll
    for (int r=0;r<4;r++)
      dst[(size_t)(b0+q*4+r)*NX_ + c0+nt*16+n16] = xcv[nt][r];
}

// ---------------------------------------------------------------------------
// Combine: S[1] = Lend[0]; S[k] = S[k-1] @ P + Lend[k-1], k = 2..7.
// P = M^32 (f32, row-major [k][n]); hi/lo f16 fragments.
// ---------------------------------------------------------------------------
extern "C" __global__ __launch_bounds__(512)
void combine(const float* __restrict__ P,
             const float* __restrict__ Lend,
             float* __restrict__ S)
{
  __shared__ __align__(16) _Float16 xb[2*XBUFSZ];

  const int tid  = threadIdx.x;
  const int lane = tid & 63;
  const int w    = tid >> 6;
  const int q    = lane >> 4;
  const int n16  = lane & 15;
  const int b0   = blockIdx.x * 16;
  const int c0   = w * 32;
  const size_t BN = (size_t)B_ROWS*NX_;

  // P B-frags hi/lo: element (n = c0+nt*16+n16, k = kk*32+q*8+j) -> P[k*NX_+n]
  half8 Ph[2][8], Pl[2][8];
  #pragma unroll
  for (int nt=0; nt<2; nt++) {
    const int n = c0 + nt*16 + n16;
    #pragma unroll
    for (int kk=0; kk<8; kk++) {
      half8 h, l;
      #pragma unroll
      for (int j=0;j<8;j++){
        float v = P[(size_t)(kk*32 + q*8 + j)*NX_ + n];
        _Float16 hi = (_Float16)v;
        h[j] = hi;
        l[j] = (_Float16)(v - (float)hi);
      }
      Ph[nt][kk]=h; Pl[nt][kk]=l;
    }
  }

  // stage s = Lend[0] into xb[0] (f16) and copy to S[1]
  {
    int row = tid >> 5, ch = tid & 31;
    const float* s = Lend + (size_t)(b0+row)*NX_ + ch*8;
    float*       o = S    + (size_t)(b0+row)*NX_ + ch*8;
    _Float16* dst = &xb[row*XPITCH + ch*8];
    #pragma unroll
    for (int j=0;j<8;j++){ float v = s[j]; dst[j] = (_Float16)v; o[j] = v; }
  }
  block_sync_lds();

  for (int k=2; k<=7; k++) {
    const int rp = (k-2)&1;
    const _Float16* xr = xb + rp*XBUFSZ;
    _Float16*       xw = xb + (rp^1)*XBUFSZ;

    // seed acc with Lend[k-1]
    const float* lsrc = Lend + (size_t)(k-1)*BN;
    f32x4 xn[2];
    #pragma unroll
    for (int nt=0;nt<2;nt++)
      #pragma unroll
      for (int r=0;r<4;r++)
        xn[nt][r] = lsrc[(size_t)(b0+q*4+r)*NX_ + c0+nt*16+n16];

    #pragma unroll
    for (int kk=0;kk<8;kk++){
      half8 xa = *(const half8*)(xr + n16*XPITCH + kk*32 + q*8);
      xn[0] = MFMA16(xa, Ph[0][kk], xn[0]);
      xn[1] = MFMA16(xa, Ph[1][kk], xn[1]);
      xn[0] = MFMA16(xa, Pl[0][kk], xn[0]);
      xn[1] = MFMA16(xa, Pl[1][kk], xn[1]);
    }

    float* sdst = S + (size_t)(k-1)*BN;
    #pragma unroll
    for (int nt=0;nt<2;nt++)
      #pragma unroll
      for (int r=0;r<4;r++){
        float z = xn[nt][r];
        sdst[(size_t)(b0+q*4+r)*NX_ + c0+nt*16+n16] = z;
        xw[(q*4+r)*XPITCH + c0+nt*16+n16] = (_Float16)z;
      }
    block_sync_lds();
  }
}

// ---------------------------------------------------------------------------
// Phase 2: full work per chunk from correct init state.
// ---------------------------------------------------------------------------
extern "C" __global__ __launch_bounds__(512, 4)
void phase2(const float* __restrict__ x0,
            const float* __restrict__ U,
            const float* __restrict__ Dd,
            const float* __restrict__ Wx,
            const float* __restrict__ bx,
            const float* __restrict__ Wu,
            const float* __restrict__ bu,
            const float* __restrict__ Wd,
            const float* __restrict__ bd,
            const float* __restrict__ Wy,
            const float* __restrict__ by,
            const float* __restrict__ S,
            float* __restrict__ Xout,
            float* __restrict__ Yout,
            float* __restrict__ Rout)
{
  __shared__ __align__(16) _Float16 xb[2*XBUFSZ];
  __shared__ __align__(16) _Float16 wyl[64*XPITCH];
  __shared__ float red[64];

  const int tid  = threadIdx.x;
  const int lane = tid & 63;
  const int w    = tid >> 6;
  const int q    = lane >> 4;
  const int n16  = lane & 15;
  const int b0   = blockIdx.x * 16;
  const int ck   = blockIdx.y;
  const int t0   = ck * CHUNK;
  const int c0   = w * 32;

  const float* init = (ck==0) ? x0 : (S + (size_t)(ck-1)*B_ROWS*NX_);

  for (int i = tid; i < 64*32; i += 512) {
    int row = i >> 5, ch = i & 31;
    const float* s = Wy + row*NX_ + ch*8;
    _Float16* dst = &wyl[row*XPITCH + ch*8];
    #pragma unroll
    for (int j=0;j<8;j++) dst[j] = (_Float16)s[j];
  }
  {
    int row = tid >> 5, ch = tid & 31;
    const float* s = init + (size_t)(b0+row)*NX_ + ch*8;
    _Float16* dst = &xb[row*XPITCH + ch*8];
    #pragma unroll
    for (int j=0;j<8;j++) dst[j] = (_Float16)s[j];
  }

  half8 Wh[2][8], Wl[2][8];
  #pragma unroll
  for (int nt=0; nt<2; nt++) {
    const int row = c0 + nt*16 + n16;
    #pragma unroll
    for (int kk=0; kk<8; kk++) {
      const float* s = Wx + row*NX_ + kk*32 + q*8;
      half8 h, l;
      #pragma unroll
      for (int j=0;j<8;j++){
        float v = s[j];
        _Float16 hi = (_Float16)v;
        h[j] = hi;
        l[j] = (_Float16)(v - (float)hi);
      }
      Wh[nt][kk]=h; Wl[nt][kk]=l;
    }
  }
  half8 WuF[2][2];
  #pragma unroll
  for (int nt=0;nt<2;nt++){
    const int row=c0+nt*16+n16;
    #pragma unroll
    for(int kk=0;kk<2;kk++){
      const float* s=Wu+row*NU_+kk*32+q*8; half8 h;
      #pragma unroll
      for(int j=0;j<8;j++) h[j]=(_Float16)s[j];
      WuF[nt][kk]=h;
    }
  }
  half8 WdF[2];
  #pragma unroll
  for(int nt=0;nt<2;nt++){
    const int row=c0+nt*16+n16;
    const float* s=Wd+row*ND_+q*8; half8 h;
    #pragma unroll
    for(int j=0;j<8;j++) h[j]=(_Float16)s[j];
    WdF[nt]=h;
  }
  const float bxs[2] = { bx[c0+n16], bx[c0+16+n16] };
  const float bus[2] = { bu[c0+n16], bu[c0+16+n16] };
  const float bds[2] = { bd[c0+n16], bd[c0+16+n16] };
  const float bys    = (w<4) ? by[w*16+n16] : 0.f;

  float xcv[2][4];
  #pragma unroll
  for(int nt=0;nt<2;nt++)
    #pragma unroll
    for(int r=0;r<4;r++)
      xcv[nt][r] = init[(size_t)(b0+q*4+r)*NX_ + c0+nt*16+n16];

  float st[7];
  #pragma unroll
  for(int i=0;i<7;i++) st[i]=0.f;

  // ---- prologue: preload u/d for t0 ----
  f32x4 u0a,u0b,u1a,u1b,d0a,d0b;
  {
    const float* usrc = U  + ((size_t)t0*B_ROWS + b0 + n16)*NU_;
    const float* dsrc = Dd + ((size_t)t0*B_ROWS + b0 + n16)*ND_;
    u0a = *(const f32x4*)(usrc + q*8);
    u0b = *(const f32x4*)(usrc + q*8 + 4);
    u1a = *(const f32x4*)(usrc + 32 + q*8);
    u1b = *(const f32x4*)(usrc + 32 + q*8 + 4);
    d0a = *(const f32x4*)(dsrc + q*8);
    d0b = *(const f32x4*)(dsrc + q*8 + 4);
  }

  block_sync_lds();

  for (int tt=0; tt<CHUNK; tt++) {
    const int t = t0 + tt;
    const _Float16* xr = xb + (tt&1)*XBUFSZ;
    _Float16*       xw = xb + ((tt&1)^1)*XBUFSZ;

    f32x4 xn[2];
    xn[0] = (f32x4){bxs[0],bxs[0],bxs[0],bxs[0]};
    xn[1] = (f32x4){bxs[1],bxs[1],bxs[1],bxs[1]};
    #pragma unroll
    for (int kk=0;kk<8;kk++){
      half8 xa = *(const half8*)(xr + n16*XPITCH + kk*32 + q*8);
      xn[0] = MFMA16(xa, Wh[0][kk], xn[0]);
      xn[1] = MFMA16(xa, Wh[1][kk], xn[1]);
      xn[0] = MFMA16(xa, Wl[0][kk], xn[0]);
      xn[1] = MFMA16(xa, Wl[1][kk], xn[1]);
    }

    half8 uf0 = cvt8(u0a,u0b), uf1 = cvt8(u1a,u1b), df = cvt8(d0a,d0b);

    // ---- prefetch u/d for t+1 (lands during epilogue + barrier + next chain) ----
    {
      const int tn = t0 + ((tt+1 < CHUNK) ? tt+1 : tt);
      const float* un = U  + ((size_t)tn*B_ROWS + b0 + n16)*NU_;
      const float* dn = Dd + ((size_t)tn*B_ROWS + b0 + n16)*ND_;
      u0a = *(const f32x4*)(un + q*8);
      u0b = *(const f32x4*)(un + q*8 + 4);
      u1a = *(const f32x4*)(un + 32 + q*8);
      u1b = *(const f32x4*)(un + 32 + q*8 + 4);
      d0a = *(const f32x4*)(dn + q*8);
      d0b = *(const f32x4*)(dn + q*8 + 4);
    }

    f32x4 fu[2], fd[2];
    fu[0] = (f32x4){bus[0],bus[0],bus[0],bus[0]};
    fu[1] = (f32x4){bus[1],bus[1],bus[1],bus[1]};
    fd[0] = (f32x4){bds[0],bds[0],bds[0],bds[0]};
    fd[1] = (f32x4){bds[1],bds[1],bds[1],bds[1]};
    fu[0] = MFMA16(uf0, WuF[0][0], fu[0]);  fu[0] = MFMA16(uf1, WuF[0][1], fu[0]);
    fu[1] = MFMA16(uf0, WuF[1][0], fu[1]);  fu[1] = MFMA16(uf1, WuF[1][1], fu[1]);
    fd[0] = MFMA16(df,  WdF[0],    fd[0]);
    fd[1] = MFMA16(df,  WdF[1],    fd[1]);

    const size_t xrowbase = (size_t)t*(B_ROWS*NX_) + (size_t)b0*NX_;
    #pragma unroll
    for (int nt=0;nt<2;nt++){
      #pragma unroll
      for (int r=0;r<4;r++){
        float f  = fu[nt][r];
        float g  = fd[nt][r];
        float z  = xn[nt][r] + f + g;
        float zc = xcv[nt][r];
        float r0 = fmaxf(-1.f - z, 0.f);
        float r1 = fmaxf( z - 1.f, 0.f);
        float r2 = fmaxf(-1.f - f, 0.f);
        float r3 = fmaxf( f - 1.f, 0.f);
        float g0 = fmaxf(-1.f - g, 0.f);
        float g1 = fmaxf( g - 1.f, 0.f);
        float dz = z - zc;
        st[0]+=r0; st[1]+=r1; st[2]+=r2; st[3]+=r3;
        st[4]+=dz*dz; st[5]+=r2+r3; st[6]+=g0+g1;
        Xout[xrowbase + (size_t)(q*4+r)*NX_ + (c0+nt*16+n16)] = z;
        xw[(q*4+r)*XPITCH + c0+nt*16+n16] = (_Float16)z;
        xcv[nt][r] = z;
      }
    }
    block_sync_lds();

    if (w < 4) {
      f32x4 ya = (f32x4){bys,bys,bys,bys};
      #pragma unroll
      for (int kk=0;kk<8;kk++){
        half8 xa = *(const half8*)(xw + n16*XPITCH + kk*32 + q*8);
        half8 wb = *(const half8*)(&wyl[(w*16+n16)*XPITCH + kk*32 + q*8]);
        ya = MFMA16(xa, wb, ya);
      }
      const size_t ybase = (size_t)t*(B_ROWS*NY_) + (size_t)b0*NY_ + w*16 + n16;
      #pragma unroll
      for (int r=0;r<4;r++)
        Yout[ybase + (size_t)(q*4+r)*NY_] = ya[r];
    }
  }

  #pragma unroll
  for (int off=32; off>=1; off>>=1){
    #pragma unroll
    for (int i=0;i<7;i++) st[i] += __shfl_down(st[i], off, 64);
  }
  __syncthreads();
  if (lane==0){
    #pragma unroll
    for (int i=0;i<7;i++) red[w*8+i] = st[i];
  }
  __syncthreads();
  if (tid==0){
    float s = 0.f;
    for (int ww=0; ww<8; ww++)
      for (int i=0;i<7;i++) s += red[ww*8+i];
    atomicAdd(Rout, s * (0.2f/67108864.0f));
  }
}

extern "C" void kernel_launch(void* const* d_in, const int* in_sizes, int n_in,
                              void* d_out, int out_size, void* d_ws, size_t ws_size,
                              hipStream_t stream)
{
  const float* x0=(const float*)d_in[0];
  const float* U =(const float*)d_in[1];
  const float* Dd=(const float*)d_in[2];
  const float* Wx=(const float*)d_in[3];
  const float* bx=(const float*)d_in[4];
  const float* Wu=(const float*)d_in[5];
  const float* bu=(const float*)d_in[6];
  const float* Wd=(const float*)d_in[7];
  const float* bd=(const float*)d_in[8];
  const float* Wy=(const float*)d_in[9];
  const float* by=(const float*)d_in[10];

  float* X = (float*)d_out;
  float* Y = X + (size_t)T_STEPS*B_ROWS*NX_;
  float* R = Y + (size_t)T_STEPS*B_ROWS*NY_;

  // workspace layout (floats)
  float* B0   = (float*)d_ws;                 // 65536
  float* B1   = B0 + 65536;                   // 65536
  float* Lend = B1 + 65536;                   // 7 * 1024*256
  float* S    = Lend + (size_t)7*B_ROWS*NX_;  // 7 * 1024*256

  hipMemsetAsync(R, 0, sizeof(float), stream);

  // P = (Wx^T)^32 via repeated squaring (f32)
  matsq<<<dim3(256), dim3(256), 0, stream>>>(Wx, B1, 1);  // M^2
  matsq<<<dim3(256), dim3(256), 0, stream>>>(B1, B0, 0);  // M^4
  matsq<<<dim3(256), dim3(256), 0, stream>>>(B0, B1, 0);  // M^8
  matsq<<<dim3(256), dim3(256), 0, stream>>>(B1, B0, 0);  // M^16
  matsq<<<dim3(256), dim3(256), 0, stream>>>(B0, B1, 0);  // M^32 -> P = B1

  phase1<<<dim3(64,7), dim3(512), 0, stream>>>(x0,U,Dd,Wx,bx,Wu,bu,Wd,bd,Lend);
  combine<<<dim3(64), dim3(512), 0, stream>>>(B1, Lend, S);
  phase2<<<dim3(64,8), dim3(512), 0, stream>>>(x0,U,Dd,Wx,bx,Wu,bu,Wd,bd,Wy,by,S,X,Y,R);
}

// Round 2
// 877.647 us; speedup vs baseline: 2.0305x; 2.0305x over previous
//
#include <hip/hip_runtime.h>

#define T_STEPS 256
#define B_ROWS  1024
#define NX_ 256
#define NY_ 64
#define NU_ 64
#define ND_ 32

#define CHUNK   32
#define NCHUNK  8          // T_STEPS / CHUNK

typedef _Float16 half8 __attribute__((ext_vector_type(8)));
typedef float    f32x4 __attribute__((ext_vector_type(4)));

#define MFMA16(a,b,c) __builtin_amdgcn_mfma_f32_16x16x32_f16((a),(b),(c),0,0,0)

#define XPITCH 264              // padded LDS row pitch (halfs): 2-way max on b128
#define XBUFSZ (16*XPITCH)

// Barrier that drains ONLY LDS (lgkmcnt) — global stores / prefetch loads stay
// in flight across it. The only cross-wave hazard per step is the LDS x-buffer.
// asm memory clobbers on both sides stop the compiler from moving LDS ops
// across the raw s_barrier.
__device__ __forceinline__ void block_sync_lds() {
  asm volatile("s_waitcnt lgkmcnt(0)" ::: "memory");
  __builtin_amdgcn_s_barrier();
  asm volatile("" ::: "memory");
}

__device__ __forceinline__ half8 cvt8(f32x4 a, f32x4 b) {
  half8 h;
  h[0]=(_Float16)a[0]; h[1]=(_Float16)a[1]; h[2]=(_Float16)a[2]; h[3]=(_Float16)a[3];
  h[4]=(_Float16)b[0]; h[5]=(_Float16)b[1]; h[6]=(_Float16)b[2]; h[7]=(_Float16)b[3];
  return h;
}

// ---------------------------------------------------------------------------
// out = in @ in (256x256 f32). from_wx: in-matrix is M = Wx^T read from Wx.
// M[r][k] = Wx[k][r]. One block per output row, one thread per column.
// ---------------------------------------------------------------------------
extern "C" __global__ __launch_bounds__(256)
void matsq(const float* __restrict__ src, float* __restrict__ dst, int from_wx)
{
  const int r = blockIdx.x, c = threadIdx.x;
  float acc = 0.f;
  if (from_wx) {
    for (int k = 0; k < NX_; k++) acc += src[k*NX_ + r] * src[c*NX_ + k];
  } else {
    for (int k = 0; k < NX_; k++) acc += src[r*NX_ + k] * src[k*NX_ + c];
  }
  dst[r*NX_ + c] = acc;
}

// ---------------------------------------------------------------------------
// Phase 1: per (row-group, chunk) scan from zero state (chunk 0: from x0).
// Stores only the chunk-final state (f32) to Lend[chunk][B][NX].
// NOTE: plain __launch_bounds__(512). The (512,4) variant forced a 64-VGPR
// cap (backend interprets the waves/EU arg 2x tighter than documented) ->
// total spill, FETCH_SIZE 63MB -> 2.8GB, 3.7x slowdown. 512-alone gives the
// proven 128-VGPR / 2-blocks-per-CU allocation.
// ---------------------------------------------------------------------------
extern "C" __global__ __launch_bounds__(512)
void phase1(const float* __restrict__ x0,
            const float* __restrict__ U,
            const float* __restrict__ Dd,
            const float* __restrict__ Wx,
            const float* __restrict__ bx,
            const float* __restrict__ Wu,
            const float* __restrict__ bu,
            const float* __restrict__ Wd,
            const float* __restrict__ bd,
            float* __restrict__ Lend)
{
  __shared__ __align__(16) _Float16 xb[2*XBUFSZ];

  const int tid  = threadIdx.x;
  const int lane = tid & 63;
  const int w    = tid >> 6;
  const int q    = lane >> 4;
  const int n16  = lane & 15;
  const int b0   = blockIdx.x * 16;
  const int ck   = blockIdx.y;          // chunk 0..6
  const int t0   = ck * CHUNK;
  const int c0   = w * 32;

  // ---- stage init state into xb[0] ----
  if (ck == 0) {
    int row = tid >> 5, ch = tid & 31;
    const float* s = x0 + (size_t)(b0+row)*NX_ + ch*8;
    _Float16* dst = &xb[row*XPITCH + ch*8];
    #pragma unroll
    for (int j=0;j<8;j++) dst[j] = (_Float16)s[j];
  } else {
    for (int i = tid; i < XBUFSZ; i += 512) xb[i] = (_Float16)0.f;
  }

  // ---- Wx hi/lo B-frags ----
  half8 Wh[2][8], Wl[2][8];
  #pragma unroll
  for (int nt=0; nt<2; nt++) {
    const int row = c0 + nt*16 + n16;
    #pragma unroll
    for (int kk=0; kk<8; kk++) {
      const float* s = Wx + row*NX_ + kk*32 + q*8;
      half8 h, l;
      #pragma unroll
      for (int j=0;j<8;j++){
        float v = s[j];
        _Float16 hi = (_Float16)v;
        h[j] = hi;
        l[j] = (_Float16)(v - (float)hi);
      }
      Wh[nt][kk]=h; Wl[nt][kk]=l;
    }
  }
  half8 WuF[2][2];
  #pragma unroll
  for (int nt=0;nt<2;nt++){
    const int row=c0+nt*16+n16;
    #pragma unroll
    for(int kk=0;kk<2;kk++){
      const float* s=Wu+row*NU_+kk*32+q*8; half8 h;
      #pragma unroll
      for(int j=0;j<8;j++) h[j]=(_Float16)s[j];
      WuF[nt][kk]=h;
    }
  }
  half8 WdF[2];
  #pragma unroll
  for(int nt=0;nt<2;nt++){
    const int row=c0+nt*16+n16;
    const float* s=Wd+row*ND_+q*8; half8 h;
    #pragma unroll
    for(int j=0;j<8;j++) h[j]=(_Float16)s[j];
    WdF[nt]=h;
  }
  const float bxs[2] = { bx[c0+n16], bx[c0+16+n16] };
  const float bus[2] = { bu[c0+n16], bu[c0+16+n16] };
  const float bds[2] = { bd[c0+n16], bd[c0+16+n16] };

  float xcv[2][4];
  #pragma unroll
  for(int nt=0;nt<2;nt++)
    #pragma unroll
    for(int r=0;r<4;r++)
      xcv[nt][r] = (ck==0) ? x0[(size_t)(b0+q*4+r)*NX_ + c0+nt*16+n16] : 0.f;

  // ---- prologue: preload u/d for t0 (stays in flight across the barrier) ----
  f32x4 u0a,u0b,u1a,u1b,d0a,d0b;
  {
    const float* usrc = U  + ((size_t)t0*B_ROWS + b0 + n16)*NU_;
    const float* dsrc = Dd + ((size_t)t0*B_ROWS + b0 + n16)*ND_;
    u0a = *(const f32x4*)(usrc + q*8);
    u0b = *(const f32x4*)(usrc + q*8 + 4);
    u1a = *(const f32x4*)(usrc + 32 + q*8);
    u1b = *(const f32x4*)(usrc + 32 + q*8 + 4);
    d0a = *(const f32x4*)(dsrc + q*8);
    d0b = *(const f32x4*)(dsrc + q*8 + 4);
  }

  block_sync_lds();

  for (int tt=0; tt<CHUNK; tt++) {
    const _Float16* xr = xb + (tt&1)*XBUFSZ;
    _Float16*       xw = xb + ((tt&1)^1)*XBUFSZ;

    f32x4 xn[2];
    xn[0] = (f32x4){bxs[0],bxs[0],bxs[0],bxs[0]};
    xn[1] = (f32x4){bxs[1],bxs[1],bxs[1],bxs[1]};
    #pragma unroll
    for (int kk=0;kk<8;kk++){
      half8 xa = *(const half8*)(xr + n16*XPITCH + kk*32 + q*8);
      xn[0] = MFMA16(xa, Wh[0][kk], xn[0]);
      xn[1] = MFMA16(xa, Wh[1][kk], xn[1]);
      xn[0] = MFMA16(xa, Wl[0][kk], xn[0]);
      xn[1] = MFMA16(xa, Wl[1][kk], xn[1]);
    }

    half8 uf0 = cvt8(u0a,u0b), uf1 = cvt8(u1a,u1b), df = cvt8(d0a,d0b);

    // ---- prefetch u/d for t+1 (WAR on regs just consumed by cvt8) ----
    {
      const int tn = t0 + ((tt+1 < CHUNK) ? tt+1 : tt);
      const float* un = U  + ((size_t)tn*B_ROWS + b0 + n16)*NU_;
      const float* dn = Dd + ((size_t)tn*B_ROWS + b0 + n16)*ND_;
      u0a = *(const f32x4*)(un + q*8);
      u0b = *(const f32x4*)(un + q*8 + 4);
      u1a = *(const f32x4*)(un + 32 + q*8);
      u1b = *(const f32x4*)(un + 32 + q*8 + 4);
      d0a = *(const f32x4*)(dn + q*8);
      d0b = *(const f32x4*)(dn + q*8 + 4);
    }

    f32x4 fu[2], fd[2];
    fu[0] = (f32x4){bus[0],bus[0],bus[0],bus[0]};
    fu[1] = (f32x4){bus[1],bus[1],bus[1],bus[1]};
    fd[0] = (f32x4){bds[0],bds[0],bds[0],bds[0]};
    fd[1] = (f32x4){bds[1],bds[1],bds[1],bds[1]};
    fu[0] = MFMA16(uf0, WuF[0][0], fu[0]);  fu[0] = MFMA16(uf1, WuF[0][1], fu[0]);
    fu[1] = MFMA16(uf0, WuF[1][0], fu[1]);  fu[1] = MFMA16(uf1, WuF[1][1], fu[1]);
    fd[0] = MFMA16(df,  WdF[0],    fd[0]);
    fd[1] = MFMA16(df,  WdF[1],    fd[1]);

    #pragma unroll
    for (int nt=0;nt<2;nt++){
      #pragma unroll
      for (int r=0;r<4;r++){
        float z = xn[nt][r] + fu[nt][r] + fd[nt][r];
        xw[(q*4+r)*XPITCH + c0+nt*16+n16] = (_Float16)z;
        xcv[nt][r] = z;
      }
    }
    block_sync_lds();
  }

  // store chunk-final state
  float* dst = Lend + (size_t)ck*(B_ROWS*NX_);
  #pragma unroll
  for (int nt=0;nt<2;nt++)
    #pragma unroll
    for (int r=0;r<4;r++)
      dst[(size_t)(b0+q*4+r)*NX_ + c0+nt*16+n16] = xcv[nt][r];
}

// ---------------------------------------------------------------------------
// Combine: S[1] = Lend[0]; S[k] = S[k-1] @ P + Lend[k-1], k = 2..7.
// P = M^32 (f32, row-major [k][n]); hi/lo f16 fragments.
// ---------------------------------------------------------------------------
extern "C" __global__ __launch_bounds__(512)
void combine(const float* __restrict__ P,
             const float* __restrict__ Lend,
             float* __restrict__ S)
{
  __shared__ __align__(16) _Float16 xb[2*XBUFSZ];

  const int tid  = threadIdx.x;
  const int lane = tid & 63;
  const int w    = tid >> 6;
  const int q    = lane >> 4;
  const int n16  = lane & 15;
  const int b0   = blockIdx.x * 16;
  const int c0   = w * 32;
  const size_t BN = (size_t)B_ROWS*NX_;

  // P B-frags hi/lo: element (n = c0+nt*16+n16, k = kk*32+q*8+j) -> P[k*NX_+n]
  half8 Ph[2][8], Pl[2][8];
  #pragma unroll
  for (int nt=0; nt<2; nt++) {
    const int n = c0 + nt*16 + n16;
    #pragma unroll
    for (int kk=0; kk<8; kk++) {
      half8 h, l;
      #pragma unroll
      for (int j=0;j<8;j++){
        float v = P[(size_t)(kk*32 + q*8 + j)*NX_ + n];
        _Float16 hi = (_Float16)v;
        h[j] = hi;
        l[j] = (_Float16)(v - (float)hi);
      }
      Ph[nt][kk]=h; Pl[nt][kk]=l;
    }
  }

  // stage s = Lend[0] into xb[0] (f16) and copy to S[1]
  {
    int row = tid >> 5, ch = tid & 31;
    const float* s = Lend + (size_t)(b0+row)*NX_ + ch*8;
    float*       o = S    + (size_t)(b0+row)*NX_ + ch*8;
    _Float16* dst = &xb[row*XPITCH + ch*8];
    #pragma unroll
    for (int j=0;j<8;j++){ float v = s[j]; dst[j] = (_Float16)v; o[j] = v; }
  }
  block_sync_lds();

  for (int k=2; k<=7; k++) {
    const int rp = (k-2)&1;
    const _Float16* xr = xb + rp*XBUFSZ;
    _Float16*       xw = xb + (rp^1)*XBUFSZ;

    // seed acc with Lend[k-1]
    const float* lsrc = Lend + (size_t)(k-1)*BN;
    f32x4 xn[2];
    #pragma unroll
    for (int nt=0;nt<2;nt++)
      #pragma unroll
      for (int r=0;r<4;r++)
        xn[nt][r] = lsrc[(size_t)(b0+q*4+r)*NX_ + c0+nt*16+n16];

    #pragma unroll
    for (int kk=0;kk<8;kk++){
      half8 xa = *(const half8*)(xr + n16*XPITCH + kk*32 + q*8);
      xn[0] = MFMA16(xa, Ph[0][kk], xn[0]);
      xn[1] = MFMA16(xa, Ph[1][kk], xn[1]);
      xn[0] = MFMA16(xa, Pl[0][kk], xn[0]);
      xn[1] = MFMA16(xa, Pl[1][kk], xn[1]);
    }

    float* sdst = S + (size_t)(k-1)*BN;
    #pragma unroll
    for (int nt=0;nt<2;nt++)
      #pragma unroll
      for (int r=0;r<4;r++){
        float z = xn[nt][r];
        sdst[(size_t)(b0+q*4+r)*NX_ + c0+nt*16+n16] = z;
        xw[(q*4+r)*XPITCH + c0+nt*16+n16] = (_Float16)z;
      }
    block_sync_lds();
  }
}

// ---------------------------------------------------------------------------
// Phase 2: full work per chunk from correct init state.
// ---------------------------------------------------------------------------
extern "C" __global__ __launch_bounds__(512)
void phase2(const float* __restrict__ x0,
            const float* __restrict__ U,
            const float* __restrict__ Dd,
            const float* __restrict__ Wx,
            const float* __restrict__ bx,
            const float* __restrict__ Wu,
            const float* __restrict__ bu,
            const float* __restrict__ Wd,
            const float* __restrict__ bd,
            const float* __restrict__ Wy,
            const float* __restrict__ by,
            const float* __restrict__ S,
            float* __restrict__ Xout,
            float* __restrict__ Yout,
            float* __restrict__ Rout)
{
  __shared__ __align__(16) _Float16 xb[2*XBUFSZ];
  __shared__ __align__(16) _Float16 wyl[64*XPITCH];
  __shared__ float red[64];

  const int tid  = threadIdx.x;
  const int lane = tid & 63;
  const int w    = tid >> 6;
  const int q    = lane >> 4;
  const int n16  = lane & 15;
  const int b0   = blockIdx.x * 16;
  const int ck   = blockIdx.y;
  const int t0   = ck * CHUNK;
  const int c0   = w * 32;

  const float* init = (ck==0) ? x0 : (S + (size_t)(ck-1)*B_ROWS*NX_);

  for (int i = tid; i < 64*32; i += 512) {
    int row = i >> 5, ch = i & 31;
    const float* s = Wy + row*NX_ + ch*8;
    _Float16* dst = &wyl[row*XPITCH + ch*8];
    #pragma unroll
    for (int j=0;j<8;j++) dst[j] = (_Float16)s[j];
  }
  {
    int row = tid >> 5, ch = tid & 31;
    const float* s = init + (size_t)(b0+row)*NX_ + ch*8;
    _Float16* dst = &xb[row*XPITCH + ch*8];
    #pragma unroll
    for (int j=0;j<8;j++) dst[j] = (_Float16)s[j];
  }

  half8 Wh[2][8], Wl[2][8];
  #pragma unroll
  for (int nt=0; nt<2; nt++) {
    const int row = c0 + nt*16 + n16;
    #pragma unroll
    for (int kk=0; kk<8; kk++) {
      const float* s = Wx + row*NX_ + kk*32 + q*8;
      half8 h, l;
      #pragma unroll
      for (int j=0;j<8;j++){
        float v = s[j];
        _Float16 hi = (_Float16)v;
        h[j] = hi;
        l[j] = (_Float16)(v - (float)hi);
      }
      Wh[nt][kk]=h; Wl[nt][kk]=l;
    }
  }
  half8 WuF[2][2];
  #pragma unroll
  for (int nt=0;nt<2;nt++){
    const int row=c0+nt*16+n16;
    #pragma unroll
    for(int kk=0;kk<2;kk++){
      const float* s=Wu+row*NU_+kk*32+q*8; half8 h;
      #pragma unroll
      for(int j=0;j<8;j++) h[j]=(_Float16)s[j];
      WuF[nt][kk]=h;
    }
  }
  half8 WdF[2];
  #pragma unroll
  for(int nt=0;nt<2;nt++){
    const int row=c0+nt*16+n16;
    const float* s=Wd+row*ND_+q*8; half8 h;
    #pragma unroll
    for(int j=0;j<8;j++) h[j]=(_Float16)s[j];
    WdF[nt]=h;
  }
  const float bxs[2] = { bx[c0+n16], bx[c0+16+n16] };
  const float bus[2] = { bu[c0+n16], bu[c0+16+n16] };
  const float bds[2] = { bd[c0+n16], bd[c0+16+n16] };
  const float bys    = (w<4) ? by[w*16+n16] : 0.f;

  float xcv[2][4];
  #pragma unroll
  for(int nt=0;nt<2;nt++)
    #pragma unroll
    for(int r=0;r<4;r++)
      xcv[nt][r] = init[(size_t)(b0+q*4+r)*NX_ + c0+nt*16+n16];

  float st[7];
  #pragma unroll
  for(int i=0;i<7;i++) st[i]=0.f;

  // ---- prologue: preload u/d for t0 ----
  f32x4 u0a,u0b,u1a,u1b,d0a,d0b;
  {
    const float* usrc = U  + ((size_t)t0*B_ROWS + b0 + n16)*NU_;
    const float* dsrc = Dd + ((size_t)t0*B_ROWS + b0 + n16)*ND_;
    u0a = *(const f32x4*)(usrc + q*8);
    u0b = *(const f32x4*)(usrc + q*8 + 4);
    u1a = *(const f32x4*)(usrc + 32 + q*8);
    u1b = *(const f32x4*)(usrc + 32 + q*8 + 4);
    d0a = *(const f32x4*)(dsrc + q*8);
    d0b = *(const f32x4*)(dsrc + q*8 + 4);
  }

  block_sync_lds();

  for (int tt=0; tt<CHUNK; tt++) {
    const int t = t0 + tt;
    const _Float16* xr = xb + (tt&1)*XBUFSZ;
    _Float16*       xw = xb + ((tt&1)^1)*XBUFSZ;

    f32x4 xn[2];
    xn[0] = (f32x4){bxs[0],bxs[0],bxs[0],bxs[0]};
    xn[1] = (f32x4){bxs[1],bxs[1],bxs[1],bxs[1]};
    #pragma unroll
    for (int kk=0;kk<8;kk++){
      half8 xa = *(const half8*)(xr + n16*XPITCH + kk*32 + q*8);
      xn[0] = MFMA16(xa, Wh[0][kk], xn[0]);
      xn[1] = MFMA16(xa, Wh[1][kk], xn[1]);
      xn[0] = MFMA16(xa, Wl[0][kk], xn[0]);
      xn[1] = MFMA16(xa, Wl[1][kk], xn[1]);
    }

    half8 uf0 = cvt8(u0a,u0b), uf1 = cvt8(u1a,u1b), df = cvt8(d0a,d0b);

    // ---- prefetch u/d for t+1 (lands during epilogue + barrier + next chain) ----
    {
      const int tn = t0 + ((tt+1 < CHUNK) ? tt+1 : tt);
      const float* un = U  + ((size_t)tn*B_ROWS + b0 + n16)*NU_;
      const float* dn = Dd + ((size_t)tn*B_ROWS + b0 + n16)*ND_;
      u0a = *(const f32x4*)(un + q*8);
      u0b = *(const f32x4*)(un + q*8 + 4);
      u1a = *(const f32x4*)(un + 32 + q*8);
      u1b = *(const f32x4*)(un + 32 + q*8 + 4);
      d0a = *(const f32x4*)(dn + q*8);
      d0b = *(const f32x4*)(dn + q*8 + 4);
    }

    f32x4 fu[2], fd[2];
    fu[0] = (f32x4){bus[0],bus[0],bus[0],bus[0]};
    fu[1] = (f32x4){bus[1],bus[1],bus[1],bus[1]};
    fd[0] = (f32x4){bds[0],bds[0],bds[0],bds[0]};
    fd[1] = (f32x4){bds[1],bds[1],bds[1],bds[1]};
    fu[0] = MFMA16(uf0, WuF[0][0], fu[0]);  fu[0] = MFMA16(uf1, WuF[0][1], fu[0]);
    fu[1] = MFMA16(uf0, WuF[1][0], fu[1]);  fu[1] = MFMA16(uf1, WuF[1][1], fu[1]);
    fd[0] = MFMA16(df,  WdF[0],    fd[0]);
    fd[1] = MFMA16(df,  WdF[1],    fd[1]);

    const size_t xrowbase = (size_t)t*(B_ROWS*NX_) + (size_t)b0*NX_;
    #pragma unroll
    for (int nt=0;nt<2;nt++){
      #pragma unroll
      for (int r=0;r<4;r++){
        float f  = fu[nt][r];
        float g  = fd[nt][r];
        float z  = xn[nt][r] + f + g;
        float zc = xcv[nt][r];
        float r0 = fmaxf(-1.f - z, 0.f);
        float r1 = fmaxf( z - 1.f, 0.f);
        float r2 = fmaxf(-1.f - f, 0.f);
        float r3 = fmaxf( f - 1.f, 0.f);
        float g0 = fmaxf(-1.f - g, 0.f);
        float g1 = fmaxf( g - 1.f, 0.f);
        float dz = z - zc;
        st[0]+=r0; st[1]+=r1; st[2]+=r2; st[3]+=r3;
        st[4]+=dz*dz; st[5]+=r2+r3; st[6]+=g0+g1;
        Xout[xrowbase + (size_t)(q*4+r)*NX_ + (c0+nt*16+n16)] = z;
        xw[(q*4+r)*XPITCH + c0+nt*16+n16] = (_Float16)z;
        xcv[nt][r] = z;
      }
    }
    block_sync_lds();

    if (w < 4) {
      f32x4 ya = (f32x4){bys,bys,bys,bys};
      #pragma unroll
      for (int kk=0;kk<8;kk++){
        half8 xa = *(const half8*)(xw + n16*XPITCH + kk*32 + q*8);
        half8 wb = *(const half8*)(&wyl[(w*16+n16)*XPITCH + kk*32 + q*8]);
        ya = MFMA16(xa, wb, ya);
      }
      const size_t ybase = (size_t)t*(B_ROWS*NY_) + (size_t)b0*NY_ + w*16 + n16;
      #pragma unroll
      for (int r=0;r<4;r++)
        Yout[ybase + (size_t)(q*4+r)*NY_] = ya[r];
    }
  }

  #pragma unroll
  for (int off=32; off>=1; off>>=1){
    #pragma unroll
    for (int i=0;i<7;i++) st[i] += __shfl_down(st[i], off, 64);
  }
  __syncthreads();
  if (lane==0){
    #pragma unroll
    for (int i=0;i<7;i++) red[w*8+i] = st[i];
  }
  __syncthreads();
  if (tid==0){
    float s = 0.f;
    for (int ww=0; ww<8; ww++)
      for (int i=0;i<7;i++) s += red[ww*8+i];
    atomicAdd(Rout, s * (0.2f/67108864.0f));
  }
}

extern "C" void kernel_launch(void* const* d_in, const int* in_sizes, int n_in,
                              void* d_out, int out_size, void* d_ws, size_t ws_size,
                              hipStream_t stream)
{
  const float* x0=(const float*)d_in[0];
  const float* U =(const float*)d_in[1];
  const float* Dd=(const float*)d_in[2];
  const float* Wx=(const float*)d_in[3];
  const float* bx=(const float*)d_in[4];
  const float* Wu=(const float*)d_in[5];
  const float* bu=(const float*)d_in[6];
  const float* Wd=(const float*)d_in[7];
  const float* bd=(const float*)d_in[8];
  const float* Wy=(const float*)d_in[9];
  const float* by=(const float*)d_in[10];

  float* X = (float*)d_out;
  float* Y = X + (size_t)T_STEPS*B_ROWS*NX_;
  float* R = Y + (size_t)T_STEPS*B_ROWS*NY_;

  // workspace layout (floats)
  float* B0   = (float*)d_ws;                 // 65536
  float* B1   = B0 + 65536;                   // 65536
  float* Lend = B1 + 65536;                   // 7 * 1024*256
  float* S    = Lend + (size_t)7*B_ROWS*NX_;  // 7 * 1024*256

  hipMemsetAsync(R, 0, sizeof(float), stream);

  // P = (Wx^T)^32 via repeated squaring (f32)
  matsq<<<dim3(256), dim3(256), 0, stream>>>(Wx, B1, 1);  // M^2
  matsq<<<dim3(256), dim3(256), 0, stream>>>(B1, B0, 0);  // M^4
  matsq<<<dim3(256), dim3(256), 0, stream>>>(B0, B1, 0);  // M^8
  matsq<<<dim3(256), dim3(256), 0, stream>>>(B1, B0, 0);  // M^16
  matsq<<<dim3(256), dim3(256), 0, stream>>>(B0, B1, 0);  // M^32 -> P = B1

  phase1<<<dim3(64,7), dim3(512), 0, stream>>>(x0,U,Dd,Wx,bx,Wu,bu,Wd,bd,Lend);
  combine<<<dim3(64), dim3(512), 0, stream>>>(B1, Lend, S);
  phase2<<<dim3(64,8), dim3(512), 0, stream>>>(x0,U,Dd,Wx,bx,Wu,bu,Wd,bd,Wy,by,S,X,Y,R);
}

// Round 4
// 793.415 us; speedup vs baseline: 2.2461x; 1.1062x over previous
//
#include <hip/hip_runtime.h>

#define T_STEPS 256
#define B_ROWS  1024
#define NX_ 256
#define NY_ 64
#define NU_ 64
#define ND_ 32

#define CHUNK   32
#define NCHUNK  8          // T_STEPS / CHUNK

typedef _Float16 half8 __attribute__((ext_vector_type(8)));
typedef float    f32x4 __attribute__((ext_vector_type(4)));

#define MFMA16(a,b,c) __builtin_amdgcn_mfma_f32_16x16x32_f16((a),(b),(c),0,0,0)

#define XPITCH 264              // padded LDS row pitch (halfs): 2-way max on b128
#define XBUFSZ (16*XPITCH)

// Barrier that drains ONLY LDS (lgkmcnt) — global stores / in-flight loads are
// NOT drained (the compiler's __syncthreads emits s_waitcnt vmcnt(0), which
// serializes X/Y store-acks into every step). The only cross-wave hazard per
// step is the LDS x-buffer, covered by lgkmcnt(0)+s_barrier.
// NOTE (R2 lesson): do NOT add register prefetch on top of this — extending
// U/D register liveness across the MFMA section causes silent scratch spill
// (FETCH +97MB) at unchanged VGPR_Count=128.
__device__ __forceinline__ void block_sync_lds() {
  asm volatile("s_waitcnt lgkmcnt(0)" ::: "memory");
  __builtin_amdgcn_s_barrier();
  asm volatile("" ::: "memory");
}

__device__ __forceinline__ half8 cvt8(f32x4 a, f32x4 b) {
  half8 h;
  h[0]=(_Float16)a[0]; h[1]=(_Float16)a[1]; h[2]=(_Float16)a[2]; h[3]=(_Float16)a[3];
  h[4]=(_Float16)b[0]; h[5]=(_Float16)b[1]; h[6]=(_Float16)b[2]; h[7]=(_Float16)b[3];
  return h;
}

// ---------------------------------------------------------------------------
// out = in @ in (256x256 f32). from_wx: in-matrix is M = Wx^T read from Wx.
// M[r][k] = Wx[k][r]. One block per output row, one thread per column.
// ---------------------------------------------------------------------------
extern "C" __global__ __launch_bounds__(256)
void matsq(const float* __restrict__ src, float* __restrict__ dst, int from_wx)
{
  const int r = blockIdx.x, c = threadIdx.x;
  float acc = 0.f;
  if (from_wx) {
    for (int k = 0; k < NX_; k++) acc += src[k*NX_ + r] * src[c*NX_ + k];
  } else {
    for (int k = 0; k < NX_; k++) acc += src[r*NX_ + k] * src[k*NX_ + c];
  }
  dst[r*NX_ + c] = acc;
}

// ---------------------------------------------------------------------------
// Phase 1: per (row-group, chunk) scan from zero state (chunk 0: from x0).
// Stores only the chunk-final state (f32) to Lend[chunk][B][NX].
// ---------------------------------------------------------------------------
extern "C" __global__ __launch_bounds__(512)
void phase1(const float* __restrict__ x0,
            const float* __restrict__ U,
            const float* __restrict__ Dd,
            const float* __restrict__ Wx,
            const float* __restrict__ bx,
            const float* __restrict__ Wu,
            const float* __restrict__ bu,
            const float* __restrict__ Wd,
            const float* __restrict__ bd,
            float* __restrict__ Lend)
{
  __shared__ __align__(16) _Float16 xb[2*XBUFSZ];

  const int tid  = threadIdx.x;
  const int lane = tid & 63;
  const int w    = tid >> 6;
  const int q    = lane >> 4;
  const int n16  = lane & 15;
  const int b0   = blockIdx.x * 16;
  const int ck   = blockIdx.y;          // chunk 0..6
  const int t0   = ck * CHUNK;
  const int c0   = w * 32;

  // ---- stage init state into xb[0] ----
  if (ck == 0) {
    int row = tid >> 5, ch = tid & 31;
    const float* s = x0 + (size_t)(b0+row)*NX_ + ch*8;
    _Float16* dst = &xb[row*XPITCH + ch*8];
    #pragma unroll
    for (int j=0;j<8;j++) dst[j] = (_Float16)s[j];
  } else {
    for (int i = tid; i < XBUFSZ; i += 512) xb[i] = (_Float16)0.f;
  }

  // ---- Wx hi/lo B-frags ----
  half8 Wh[2][8], Wl[2][8];
  #pragma unroll
  for (int nt=0; nt<2; nt++) {
    const int row = c0 + nt*16 + n16;
    #pragma unroll
    for (int kk=0; kk<8; kk++) {
      const float* s = Wx + row*NX_ + kk*32 + q*8;
      half8 h, l;
      #pragma unroll
      for (int j=0;j<8;j++){
        float v = s[j];
        _Float16 hi = (_Float16)v;
        h[j] = hi;
        l[j] = (_Float16)(v - (float)hi);
      }
      Wh[nt][kk]=h; Wl[nt][kk]=l;
    }
  }
  half8 WuF[2][2];
  #pragma unroll
  for (int nt=0;nt<2;nt++){
    const int row=c0+nt*16+n16;
    #pragma unroll
    for(int kk=0;kk<2;kk++){
      const float* s=Wu+row*NU_+kk*32+q*8; half8 h;
      #pragma unroll
      for(int j=0;j<8;j++) h[j]=(_Float16)s[j];
      WuF[nt][kk]=h;
    }
  }
  half8 WdF[2];
  #pragma unroll
  for(int nt=0;nt<2;nt++){
    const int row=c0+nt*16+n16;
    const float* s=Wd+row*ND_+q*8; half8 h;
    #pragma unroll
    for(int j=0;j<8;j++) h[j]=(_Float16)s[j];
    WdF[nt]=h;
  }
  const float bxs[2] = { bx[c0+n16], bx[c0+16+n16] };
  const float bus[2] = { bu[c0+n16], bu[c0+16+n16] };
  const float bds[2] = { bd[c0+n16], bd[c0+16+n16] };

  float xcv[2][4];
  #pragma unroll
  for(int nt=0;nt<2;nt++)
    #pragma unroll
    for(int r=0;r<4;r++)
      xcv[nt][r] = (ck==0) ? x0[(size_t)(b0+q*4+r)*NX_ + c0+nt*16+n16] : 0.f;

  block_sync_lds();

  for (int tt=0; tt<CHUNK; tt++) {
    const int t = t0 + tt;
    const _Float16* xr = xb + (tt&1)*XBUFSZ;
    _Float16*       xw = xb + ((tt&1)^1)*XBUFSZ;

    const float* usrc = U  + ((size_t)t*B_ROWS + b0 + n16)*NU_;
    const float* dsrc = Dd + ((size_t)t*B_ROWS + b0 + n16)*ND_;
    f32x4 u0a = *(const f32x4*)(usrc + q*8);
    f32x4 u0b = *(const f32x4*)(usrc + q*8 + 4);
    f32x4 u1a = *(const f32x4*)(usrc + 32 + q*8);
    f32x4 u1b = *(const f32x4*)(usrc + 32 + q*8 + 4);
    f32x4 d0a = *(const f32x4*)(dsrc + q*8);
    f32x4 d0b = *(const f32x4*)(dsrc + q*8 + 4);

    f32x4 xn[2];
    xn[0] = (f32x4){bxs[0],bxs[0],bxs[0],bxs[0]};
    xn[1] = (f32x4){bxs[1],bxs[1],bxs[1],bxs[1]};
    #pragma unroll
    for (int kk=0;kk<8;kk++){
      half8 xa = *(const half8*)(xr + n16*XPITCH + kk*32 + q*8);
      xn[0] = MFMA16(xa, Wh[0][kk], xn[0]);
      xn[1] = MFMA16(xa, Wh[1][kk], xn[1]);
      xn[0] = MFMA16(xa, Wl[0][kk], xn[0]);
      xn[1] = MFMA16(xa, Wl[1][kk], xn[1]);
    }

    half8 uf0 = cvt8(u0a,u0b), uf1 = cvt8(u1a,u1b), df = cvt8(d0a,d0b);
    f32x4 fu[2], fd[2];
    fu[0] = (f32x4){bus[0],bus[0],bus[0],bus[0]};
    fu[1] = (f32x4){bus[1],bus[1],bus[1],bus[1]};
    fd[0] = (f32x4){bds[0],bds[0],bds[0],bds[0]};
    fd[1] = (f32x4){bds[1],bds[1],bds[1],bds[1]};
    fu[0] = MFMA16(uf0, WuF[0][0], fu[0]);  fu[0] = MFMA16(uf1, WuF[0][1], fu[0]);
    fu[1] = MFMA16(uf0, WuF[1][0], fu[1]);  fu[1] = MFMA16(uf1, WuF[1][1], fu[1]);
    fd[0] = MFMA16(df,  WdF[0],    fd[0]);
    fd[1] = MFMA16(df,  WdF[1],    fd[1]);

    #pragma unroll
    for (int nt=0;nt<2;nt++){
      #pragma unroll
      for (int r=0;r<4;r++){
        float z = xn[nt][r] + fu[nt][r] + fd[nt][r];
        xw[(q*4+r)*XPITCH + c0+nt*16+n16] = (_Float16)z;
        xcv[nt][r] = z;
      }
    }
    block_sync_lds();
  }

  // store chunk-final state
  float* dst = Lend + (size_t)ck*(B_ROWS*NX_);
  #pragma unroll
  for (int nt=0;nt<2;nt++)
    #pragma unroll
    for (int r=0;r<4;r++)
      dst[(size_t)(b0+q*4+r)*NX_ + c0+nt*16+n16] = xcv[nt][r];
}

// ---------------------------------------------------------------------------
// Combine: S[1] = Lend[0]; S[k] = S[k-1] @ P + Lend[k-1], k = 2..7.
// P = M^32 (f32, row-major [k][n]); hi/lo f16 fragments.
// ---------------------------------------------------------------------------
extern "C" __global__ __launch_bounds__(512)
void combine(const float* __restrict__ P,
             const float* __restrict__ Lend,
             float* __restrict__ S)
{
  __shared__ __align__(16) _Float16 xb[2*XBUFSZ];

  const int tid  = threadIdx.x;
  const int lane = tid & 63;
  const int w    = tid >> 6;
  const int q    = lane >> 4;
  const int n16  = lane & 15;
  const int b0   = blockIdx.x * 16;
  const int c0   = w * 32;
  const size_t BN = (size_t)B_ROWS*NX_;

  // P B-frags hi/lo: element (n = c0+nt*16+n16, k = kk*32+q*8+j) -> P[k*NX_+n]
  half8 Ph[2][8], Pl[2][8];
  #pragma unroll
  for (int nt=0; nt<2; nt++) {
    const int n = c0 + nt*16 + n16;
    #pragma unroll
    for (int kk=0; kk<8; kk++) {
      half8 h, l;
      #pragma unroll
      for (int j=0;j<8;j++){
        float v = P[(size_t)(kk*32 + q*8 + j)*NX_ + n];
        _Float16 hi = (_Float16)v;
        h[j] = hi;
        l[j] = (_Float16)(v - (float)hi);
      }
      Ph[nt][kk]=h; Pl[nt][kk]=l;
    }
  }

  // stage s = Lend[0] into xb[0] (f16) and copy to S[1]
  {
    int row = tid >> 5, ch = tid & 31;
    const float* s = Lend + (size_t)(b0+row)*NX_ + ch*8;
    float*       o = S    + (size_t)(b0+row)*NX_ + ch*8;
    _Float16* dst = &xb[row*XPITCH + ch*8];
    #pragma unroll
    for (int j=0;j<8;j++){ float v = s[j]; dst[j] = (_Float16)v; o[j] = v; }
  }
  block_sync_lds();

  for (int k=2; k<=7; k++) {
    const int rp = (k-2)&1;
    const _Float16* xr = xb + rp*XBUFSZ;
    _Float16*       xw = xb + (rp^1)*XBUFSZ;

    // seed acc with Lend[k-1]
    const float* lsrc = Lend + (size_t)(k-1)*BN;
    f32x4 xn[2];
    #pragma unroll
    for (int nt=0;nt<2;nt++)
      #pragma unroll
      for (int r=0;r<4;r++)
        xn[nt][r] = lsrc[(size_t)(b0+q*4+r)*NX_ + c0+nt*16+n16];

    #pragma unroll
    for (int kk=0;kk<8;kk++){
      half8 xa = *(const half8*)(xr + n16*XPITCH + kk*32 + q*8);
      xn[0] = MFMA16(xa, Ph[0][kk], xn[0]);
      xn[1] = MFMA16(xa, Ph[1][kk], xn[1]);
      xn[0] = MFMA16(xa, Pl[0][kk], xn[0]);
      xn[1] = MFMA16(xa, Pl[1][kk], xn[1]);
    }

    float* sdst = S + (size_t)(k-1)*BN;
    #pragma unroll
    for (int nt=0;nt<2;nt++)
      #pragma unroll
      for (int r=0;r<4;r++){
        float z = xn[nt][r];
        sdst[(size_t)(b0+q*4+r)*NX_ + c0+nt*16+n16] = z;
        xw[(q*4+r)*XPITCH + c0+nt*16+n16] = (_Float16)z;
      }
    block_sync_lds();
  }
}

// ---------------------------------------------------------------------------
// Phase 2: full work per chunk from correct init state.
// ---------------------------------------------------------------------------
extern "C" __global__ __launch_bounds__(512)
void phase2(const float* __restrict__ x0,
            const float* __restrict__ U,
            const float* __restrict__ Dd,
            const float* __restrict__ Wx,
            const float* __restrict__ bx,
            const float* __restrict__ Wu,
            const float* __restrict__ bu,
            const float* __restrict__ Wd,
            const float* __restrict__ bd,
            const float* __restrict__ Wy,
            const float* __restrict__ by,
            const float* __restrict__ S,
            float* __restrict__ Xout,
            float* __restrict__ Yout,
            float* __restrict__ Rout)
{
  __shared__ __align__(16) _Float16 xb[2*XBUFSZ];
  __shared__ __align__(16) _Float16 wyl[64*XPITCH];
  __shared__ float red[64];

  const int tid  = threadIdx.x;
  const int lane = tid & 63;
  const int w    = tid >> 6;
  const int q    = lane >> 4;
  const int n16  = lane & 15;
  const int b0   = blockIdx.x * 16;
  const int ck   = blockIdx.y;
  const int t0   = ck * CHUNK;
  const int c0   = w * 32;

  const float* init = (ck==0) ? x0 : (S + (size_t)(ck-1)*B_ROWS*NX_);

  for (int i = tid; i < 64*32; i += 512) {
    int row = i >> 5, ch = i & 31;
    const float* s = Wy + row*NX_ + ch*8;
    _Float16* dst = &wyl[row*XPITCH + ch*8];
    #pragma unroll
    for (int j=0;j<8;j++) dst[j] = (_Float16)s[j];
  }
  {
    int row = tid >> 5, ch = tid & 31;
    const float* s = init + (size_t)(b0+row)*NX_ + ch*8;
    _Float16* dst = &xb[row*XPITCH + ch*8];
    #pragma unroll
    for (int j=0;j<8;j++) dst[j] = (_Float16)s[j];
  }

  half8 Wh[2][8], Wl[2][8];
  #pragma unroll
  for (int nt=0; nt<2; nt++) {
    const int row = c0 + nt*16 + n16;
    #pragma unroll
    for (int kk=0; kk<8; kk++) {
      const float* s = Wx + row*NX_ + kk*32 + q*8;
      half8 h, l;
      #pragma unroll
      for (int j=0;j<8;j++){
        float v = s[j];
        _Float16 hi = (_Float16)v;
        h[j] = hi;
        l[j] = (_Float16)(v - (float)hi);
      }
      Wh[nt][kk]=h; Wl[nt][kk]=l;
    }
  }
  half8 WuF[2][2];
  #pragma unroll
  for (int nt=0;nt<2;nt++){
    const int row=c0+nt*16+n16;
    #pragma unroll
    for(int kk=0;kk<2;kk++){
      const float* s=Wu+row*NU_+kk*32+q*8; half8 h;
      #pragma unroll
      for(int j=0;j<8;j++) h[j]=(_Float16)s[j];
      WuF[nt][kk]=h;
    }
  }
  half8 WdF[2];
  #pragma unroll
  for(int nt=0;nt<2;nt++){
    const int row=c0+nt*16+n16;
    const float* s=Wd+row*ND_+q*8; half8 h;
    #pragma unroll
    for(int j=0;j<8;j++) h[j]=(_Float16)s[j];
    WdF[nt]=h;
  }
  const float bxs[2] = { bx[c0+n16], bx[c0+16+n16] };
  const float bus[2] = { bu[c0+n16], bu[c0+16+n16] };
  const float bds[2] = { bd[c0+n16], bd[c0+16+n16] };
  const float bys    = (w<4) ? by[w*16+n16] : 0.f;

  float xcv[2][4];
  #pragma unroll
  for(int nt=0;nt<2;nt++)
    #pragma unroll
    for(int r=0;r<4;r++)
      xcv[nt][r] = init[(size_t)(b0+q*4+r)*NX_ + c0+nt*16+n16];

  float st[7];
  #pragma unroll
  for(int i=0;i<7;i++) st[i]=0.f;

  block_sync_lds();

  for (int tt=0; tt<CHUNK; tt++) {
    const int t = t0 + tt;
    const _Float16* xr = xb + (tt&1)*XBUFSZ;
    _Float16*       xw = xb + ((tt&1)^1)*XBUFSZ;

    const float* usrc = U  + ((size_t)t*B_ROWS + b0 + n16)*NU_;
    const float* dsrc = Dd + ((size_t)t*B_ROWS + b0 + n16)*ND_;
    f32x4 u0a = *(const f32x4*)(usrc + q*8);
    f32x4 u0b = *(const f32x4*)(usrc + q*8 + 4);
    f32x4 u1a = *(const f32x4*)(usrc + 32 + q*8);
    f32x4 u1b = *(const f32x4*)(usrc + 32 + q*8 + 4);
    f32x4 d0a = *(const f32x4*)(dsrc + q*8);
    f32x4 d0b = *(const f32x4*)(dsrc + q*8 + 4);

    f32x4 xn[2];
    xn[0] = (f32x4){bxs[0],bxs[0],bxs[0],bxs[0]};
    xn[1] = (f32x4){bxs[1],bxs[1],bxs[1],bxs[1]};
    #pragma unroll
    for (int kk=0;kk<8;kk++){
      half8 xa = *(const half8*)(xr + n16*XPITCH + kk*32 + q*8);
      xn[0] = MFMA16(xa, Wh[0][kk], xn[0]);
      xn[1] = MFMA16(xa, Wh[1][kk], xn[1]);
      xn[0] = MFMA16(xa, Wl[0][kk], xn[0]);
      xn[1] = MFMA16(xa, Wl[1][kk], xn[1]);
    }

    half8 uf0 = cvt8(u0a,u0b), uf1 = cvt8(u1a,u1b), df = cvt8(d0a,d0b);
    f32x4 fu[2], fd[2];
    fu[0] = (f32x4){bus[0],bus[0],bus[0],bus[0]};
    fu[1] = (f32x4){bus[1],bus[1],bus[1],bus[1]};
    fd[0] = (f32x4){bds[0],bds[0],bds[0],bds[0]};
    fd[1] = (f32x4){bds[1],bds[1],bds[1],bds[1]};
    fu[0] = MFMA16(uf0, WuF[0][0], fu[0]);  fu[0] = MFMA16(uf1, WuF[0][1], fu[0]);
    fu[1] = MFMA16(uf0, WuF[1][0], fu[1]);  fu[1] = MFMA16(uf1, WuF[1][1], fu[1]);
    fd[0] = MFMA16(df,  WdF[0],    fd[0]);
    fd[1] = MFMA16(df,  WdF[1],    fd[1]);

    const size_t xrowbase = (size_t)t*(B_ROWS*NX_) + (size_t)b0*NX_;
    #pragma unroll
    for (int nt=0;nt<2;nt++){
      #pragma unroll
      for (int r=0;r<4;r++){
        float f  = fu[nt][r];
        float g  = fd[nt][r];
        float z  = xn[nt][r] + f + g;
        float zc = xcv[nt][r];
        float r0 = fmaxf(-1.f - z, 0.f);
        float r1 = fmaxf( z - 1.f, 0.f);
        float r2 = fmaxf(-1.f - f, 0.f);
        float r3 = fmaxf( f - 1.f, 0.f);
        float g0 = fmaxf(-1.f - g, 0.f);
        float g1 = fmaxf( g - 1.f, 0.f);
        float dz = z - zc;
        st[0]+=r0; st[1]+=r1; st[2]+=r2; st[3]+=r3;
        st[4]+=dz*dz; st[5]+=r2+r3; st[6]+=g0+g1;
        Xout[xrowbase + (size_t)(q*4+r)*NX_ + (c0+nt*16+n16)] = z;
        xw[(q*4+r)*XPITCH + c0+nt*16+n16] = (_Float16)z;
        xcv[nt][r] = z;
      }
    }
    block_sync_lds();

    if (w < 4) {
      f32x4 ya = (f32x4){bys,bys,bys,bys};
      #pragma unroll
      for (int kk=0;kk<8;kk++){
        half8 xa = *(const half8*)(xw + n16*XPITCH + kk*32 + q*8);
        half8 wb = *(const half8*)(&wyl[(w*16+n16)*XPITCH + kk*32 + q*8]);
        ya = MFMA16(xa, wb, ya);
      }
      const size_t ybase = (size_t)t*(B_ROWS*NY_) + (size_t)b0*NY_ + w*16 + n16;
      #pragma unroll
      for (int r=0;r<4;r++)
        Yout[ybase + (size_t)(q*4+r)*NY_] = ya[r];
    }
  }

  #pragma unroll
  for (int off=32; off>=1; off>>=1){
    #pragma unroll
    for (int i=0;i<7;i++) st[i] += __shfl_down(st[i], off, 64);
  }
  __syncthreads();
  if (lane==0){
    #pragma unroll
    for (int i=0;i<7;i++) red[w*8+i] = st[i];
  }
  __syncthreads();
  if (tid==0){
    float s = 0.f;
    for (int ww=0; ww<8; ww++)
      for (int i=0;i<7;i++) s += red[ww*8+i];
    atomicAdd(Rout, s * (0.2f/67108864.0f));
  }
}

extern "C" void kernel_launch(void* const* d_in, const int* in_sizes, int n_in,
                              void* d_out, int out_size, void* d_ws, size_t ws_size,
                              hipStream_t stream)
{
  const float* x0=(const float*)d_in[0];
  const float* U =(const float*)d_in[1];
  const float* Dd=(const float*)d_in[2];
  const float* Wx=(const float*)d_in[3];
  const float* bx=(const float*)d_in[4];
  const float* Wu=(const float*)d_in[5];
  const float* bu=(const float*)d_in[6];
  const float* Wd=(const float*)d_in[7];
  const float* bd=(const float*)d_in[8];
  const float* Wy=(const float*)d_in[9];
  const float* by=(const float*)d_in[10];

  float* X = (float*)d_out;
  float* Y = X + (size_t)T_STEPS*B_ROWS*NX_;
  float* R = Y + (size_t)T_STEPS*B_ROWS*NY_;

  // workspace layout (floats)
  float* B0   = (float*)d_ws;                 // 65536
  float* B1   = B0 + 65536;                   // 65536
  float* Lend = B1 + 65536;                   // 7 * 1024*256
  float* S    = Lend + (size_t)7*B_ROWS*NX_;  // 7 * 1024*256

  hipMemsetAsync(R, 0, sizeof(float), stream);

  // P = (Wx^T)^32 via repeated squaring (f32)
  matsq<<<dim3(256), dim3(256), 0, stream>>>(Wx, B1, 1);  // M^2
  matsq<<<dim3(256), dim3(256), 0, stream>>>(B1, B0, 0);  // M^4
  matsq<<<dim3(256), dim3(256), 0, stream>>>(B0, B1, 0);  // M^8
  matsq<<<dim3(256), dim3(256), 0, stream>>>(B1, B0, 0);  // M^16
  matsq<<<dim3(256), dim3(256), 0, stream>>>(B0, B1, 0);  // M^32 -> P = B1

  phase1<<<dim3(64,7), dim3(512), 0, stream>>>(x0,U,Dd,Wx,bx,Wu,bu,Wd,bd,Lend);
  combine<<<dim3(64), dim3(512), 0, stream>>>(B1, Lend, S);
  phase2<<<dim3(64,8), dim3(512), 0, stream>>>(x0,U,Dd,Wx,bx,Wu,bu,Wd,bd,Wy,by,S,X,Y,R);
}

// Round 5
// 627.367 us; speedup vs baseline: 2.8405x; 1.2647x over previous
//
#include <hip/hip_runtime.h>

#define T_STEPS 256
#define B_ROWS  1024
#define NX_ 256
#define NY_ 64
#define NU_ 64
#define ND_ 32

#define CHUNK   32
#define NCHUNK  8          // T_STEPS / CHUNK

typedef _Float16 half8  __attribute__((ext_vector_type(8)));
typedef _Float16 half4v __attribute__((ext_vector_type(4)));
typedef float    f32x4  __attribute__((ext_vector_type(4)));

#define MFMA16(a,b,c) __builtin_amdgcn_mfma_f32_16x16x32_f16((a),(b),(c),0,0,0)

#define XPITCH 264              // padded LDS row pitch (halfs) for x-buffer
#define XBUFSZ (16*XPITCH)

// U/D staging tiles (f16, double-buffered). Pitches padded so the per-wave
// ds_read_b128 frag reads (lane n16 reads row n16) hit min-phase bank
// patterns: UP=72 halves -> 144B pitch (36 dw, %32==4 -> (n16+q)%8 spread);
// DP=40 halves -> 80B pitch (20 dw -> (5*n16+q)%8 bijective spread).
#define UP 72
#define DP 40
#define UBUFH (16*UP)           // 1152 halves
#define DBUFH (16*DP)           // 640 halves

// Barrier that drains ONLY LDS (lgkmcnt) — global stores / in-flight loads are
// NOT drained (the compiler's __syncthreads emits s_waitcnt vmcnt(0), which
// serializes X/Y store-acks into every step). Proven: R4 phase2 278->254us.
// The only cross-wave hazard per step is LDS, covered by lgkmcnt(0)+s_barrier.
__device__ __forceinline__ void block_sync_lds() {
  asm volatile("s_waitcnt lgkmcnt(0)" ::: "memory");
  __builtin_amdgcn_s_barrier();
  asm volatile("" ::: "memory");
}

__device__ __forceinline__ half4v cvt4(f32x4 a) {
  half4v h;
  h[0]=(_Float16)a[0]; h[1]=(_Float16)a[1]; h[2]=(_Float16)a[2]; h[3]=(_Float16)a[3];
  return h;
}

// ---------------------------------------------------------------------------
// out = in @ in (256x256 f32). from_wx: in-matrix is M = Wx^T read from Wx.
// ---------------------------------------------------------------------------
extern "C" __global__ __launch_bounds__(256)
void matsq(const float* __restrict__ src, float* __restrict__ dst, int from_wx)
{
  const int r = blockIdx.x, c = threadIdx.x;
  float acc = 0.f;
  if (from_wx) {
    for (int k = 0; k < NX_; k++) acc += src[k*NX_ + r] * src[c*NX_ + k];
  } else {
    for (int k = 0; k < NX_; k++) acc += src[r*NX_ + k] * src[k*NX_ + c];
  }
  dst[r*NX_ + c] = acc;
}

// ---------------------------------------------------------------------------
// Phase 1: per (row-group, chunk) scan from zero state (chunk 0: from x0).
// U/D tiles staged cooperatively to LDS (f16) once per block per step —
// previously all 8 waves loaded identical data from global (8x redundant VMEM
// + 8x redundant cvt chains). Staging prefetch = 4 VGPR/thread (R2's 24-reg
// frag prefetch spilled; this does not).
// ---------------------------------------------------------------------------
extern "C" __global__ __launch_bounds__(512)
void phase1(const float* __restrict__ x0,
            const float* __restrict__ U,
            const float* __restrict__ Dd,
            const float* __restrict__ Wx,
            const float* __restrict__ bx,
            const float* __restrict__ Wu,
            const float* __restrict__ bu,
            const float* __restrict__ Wd,
            const float* __restrict__ bd,
            float* __restrict__ Lend)
{
  __shared__ __align__(16) _Float16 xb[2*XBUFSZ];
  __shared__ __align__(16) _Float16 ub[2*UBUFH];
  __shared__ __align__(16) _Float16 db[2*DBUFH];

  const int tid  = threadIdx.x;
  const int lane = tid & 63;
  const int w    = tid >> 6;
  const int q    = lane >> 4;
  const int n16  = lane & 15;
  const int b0   = blockIdx.x * 16;
  const int ck   = blockIdx.y;          // chunk 0..6
  const int t0   = ck * CHUNK;
  const int c0   = w * 32;

  // staging roles: threads 0..255 -> U tile (16x64), 256..383 -> D (16x32)
  const bool isU = (tid < 256);
  const bool isD = (tid >= 256) && (tid < 384);
  const int  srow = isU ? (tid >> 4) : ((tid - 256) >> 3);
  const int  sch  = isU ? (tid & 15) : ((tid - 256) & 7);
  const float* sgbase = isU ? (U  + (size_t)(b0 + srow)*NU_ + sch*4)
                            : (Dd + (size_t)(b0 + srow)*ND_ + sch*4);
  const size_t sstep  = (size_t)B_ROWS * (isU ? NU_ : ND_);
  _Float16* sldsbase  = isU ? (ub + srow*UP + sch*4) : (db + srow*DP + sch*4);
  const int  sbufstep = isU ? UBUFH : DBUFH;

  // ---- stage init state into xb[0] ----
  if (ck == 0) {
    int row = tid >> 5, ch = tid & 31;
    const float* s = x0 + (size_t)(b0+row)*NX_ + ch*8;
    _Float16* dst = &xb[row*XPITCH + ch*8];
    #pragma unroll
    for (int j=0;j<8;j++) dst[j] = (_Float16)s[j];
  } else {
    for (int i = tid; i < XBUFSZ; i += 512) xb[i] = (_Float16)0.f;
  }

  // ---- stage U/D for t0 into buf 0 ----
  if (isU || isD) {
    f32x4 v = *(const f32x4*)(sgbase + (size_t)t0*sstep);
    *(half4v*)sldsbase = cvt4(v);
  }

  // ---- Wx hi/lo B-frags ----
  half8 Wh[2][8], Wl[2][8];
  #pragma unroll
  for (int nt=0; nt<2; nt++) {
    const int row = c0 + nt*16 + n16;
    #pragma unroll
    for (int kk=0; kk<8; kk++) {
      const float* s = Wx + row*NX_ + kk*32 + q*8;
      half8 h, l;
      #pragma unroll
      for (int j=0;j<8;j++){
        float v = s[j];
        _Float16 hi = (_Float16)v;
        h[j] = hi;
        l[j] = (_Float16)(v - (float)hi);
      }
      Wh[nt][kk]=h; Wl[nt][kk]=l;
    }
  }
  half8 WuF[2][2];
  #pragma unroll
  for (int nt=0;nt<2;nt++){
    const int row=c0+nt*16+n16;
    #pragma unroll
    for(int kk=0;kk<2;kk++){
      const float* s=Wu+row*NU_+kk*32+q*8; half8 h;
      #pragma unroll
      for(int j=0;j<8;j++) h[j]=(_Float16)s[j];
      WuF[nt][kk]=h;
    }
  }
  half8 WdF[2];
  #pragma unroll
  for(int nt=0;nt<2;nt++){
    const int row=c0+nt*16+n16;
    const float* s=Wd+row*ND_+q*8; half8 h;
    #pragma unroll
    for(int j=0;j<8;j++) h[j]=(_Float16)s[j];
    WdF[nt]=h;
  }
  const float bxs[2] = { bx[c0+n16], bx[c0+16+n16] };
  const float bus[2] = { bu[c0+n16], bu[c0+16+n16] };
  const float bds[2] = { bd[c0+n16], bd[c0+16+n16] };

  float xcv[2][4];
  #pragma unroll
  for(int nt=0;nt<2;nt++)
    #pragma unroll
    for(int r=0;r<4;r++)
      xcv[nt][r] = (ck==0) ? x0[(size_t)(b0+q*4+r)*NX_ + c0+nt*16+n16] : 0.f;

  block_sync_lds();

  for (int tt=0; tt<CHUNK; tt++) {
    const int cur = tt&1;
    const _Float16* xr = xb + cur*XBUFSZ;
    _Float16*       xw = xb + (cur^1)*XBUFSZ;

    // (A) prefetch next step's U/D tile into 4 regs (latency hidden by body)
    f32x4 pre;
    {
      const int tn = (tt+1 < CHUNK) ? (t0+tt+1) : (t0+tt);
      if (isU || isD) pre = *(const f32x4*)(sgbase + (size_t)tn*sstep);
    }

    // (B) frag reads from LDS (pre-converted f16; single b128 each)
    const _Float16* ubr = ub + cur*UBUFH;
    const _Float16* dbr = db + cur*DBUFH;
    half8 uf0 = *(const half8*)(ubr + n16*UP + q*8);
    half8 uf1 = *(const half8*)(ubr + n16*UP + 32 + q*8);
    half8 df  = *(const half8*)(dbr + n16*DP + q*8);

    f32x4 xn[2];
    xn[0] = (f32x4){bxs[0],bxs[0],bxs[0],bxs[0]};
    xn[1] = (f32x4){bxs[1],bxs[1],bxs[1],bxs[1]};
    #pragma unroll
    for (int kk=0;kk<8;kk++){
      half8 xa = *(const half8*)(xr + n16*XPITCH + kk*32 + q*8);
      xn[0] = MFMA16(xa, Wh[0][kk], xn[0]);
      xn[1] = MFMA16(xa, Wh[1][kk], xn[1]);
      xn[0] = MFMA16(xa, Wl[0][kk], xn[0]);
      xn[1] = MFMA16(xa, Wl[1][kk], xn[1]);
    }

    f32x4 fu[2], fd[2];
    fu[0] = (f32x4){bus[0],bus[0],bus[0],bus[0]};
    fu[1] = (f32x4){bus[1],bus[1],bus[1],bus[1]};
    fd[0] = (f32x4){bds[0],bds[0],bds[0],bds[0]};
    fd[1] = (f32x4){bds[1],bds[1],bds[1],bds[1]};
    fu[0] = MFMA16(uf0, WuF[0][0], fu[0]);  fu[0] = MFMA16(uf1, WuF[0][1], fu[0]);
    fu[1] = MFMA16(uf0, WuF[1][0], fu[1]);  fu[1] = MFMA16(uf1, WuF[1][1], fu[1]);
    fd[0] = MFMA16(df,  WdF[0],    fd[0]);
    fd[1] = MFMA16(df,  WdF[1],    fd[1]);

    #pragma unroll
    for (int nt=0;nt<2;nt++){
      #pragma unroll
      for (int r=0;r<4;r++){
        float z = xn[nt][r] + fu[nt][r] + fd[nt][r];
        xw[(q*4+r)*XPITCH + c0+nt*16+n16] = (_Float16)z;
        xcv[nt][r] = z;
      }
    }

    // (C) publish prefetched tile into the other buffer
    if (isU || isD) *(half4v*)(sldsbase + (cur^1)*sbufstep) = cvt4(pre);

    block_sync_lds();
  }

  // store chunk-final state
  float* dst = Lend + (size_t)ck*(B_ROWS*NX_);
  #pragma unroll
  for (int nt=0;nt<2;nt++)
    #pragma unroll
    for (int r=0;r<4;r++)
      dst[(size_t)(b0+q*4+r)*NX_ + c0+nt*16+n16] = xcv[nt][r];
}

// ---------------------------------------------------------------------------
// Combine: S[1] = Lend[0]; S[k] = S[k-1] @ P + Lend[k-1], k = 2..7.
// ---------------------------------------------------------------------------
extern "C" __global__ __launch_bounds__(512)
void combine(const float* __restrict__ P,
             const float* __restrict__ Lend,
             float* __restrict__ S)
{
  __shared__ __align__(16) _Float16 xb[2*XBUFSZ];

  const int tid  = threadIdx.x;
  const int lane = tid & 63;
  const int w    = tid >> 6;
  const int q    = lane >> 4;
  const int n16  = lane & 15;
  const int b0   = blockIdx.x * 16;
  const int c0   = w * 32;
  const size_t BN = (size_t)B_ROWS*NX_;

  half8 Ph[2][8], Pl[2][8];
  #pragma unroll
  for (int nt=0; nt<2; nt++) {
    const int n = c0 + nt*16 + n16;
    #pragma unroll
    for (int kk=0; kk<8; kk++) {
      half8 h, l;
      #pragma unroll
      for (int j=0;j<8;j++){
        float v = P[(size_t)(kk*32 + q*8 + j)*NX_ + n];
        _Float16 hi = (_Float16)v;
        h[j] = hi;
        l[j] = (_Float16)(v - (float)hi);
      }
      Ph[nt][kk]=h; Pl[nt][kk]=l;
    }
  }

  {
    int row = tid >> 5, ch = tid & 31;
    const float* s = Lend + (size_t)(b0+row)*NX_ + ch*8;
    float*       o = S    + (size_t)(b0+row)*NX_ + ch*8;
    _Float16* dst = &xb[row*XPITCH + ch*8];
    #pragma unroll
    for (int j=0;j<8;j++){ float v = s[j]; dst[j] = (_Float16)v; o[j] = v; }
  }
  block_sync_lds();

  for (int k=2; k<=7; k++) {
    const int rp = (k-2)&1;
    const _Float16* xr = xb + rp*XBUFSZ;
    _Float16*       xw = xb + (rp^1)*XBUFSZ;

    const float* lsrc = Lend + (size_t)(k-1)*BN;
    f32x4 xn[2];
    #pragma unroll
    for (int nt=0;nt<2;nt++)
      #pragma unroll
      for (int r=0;r<4;r++)
        xn[nt][r] = lsrc[(size_t)(b0+q*4+r)*NX_ + c0+nt*16+n16];

    #pragma unroll
    for (int kk=0;kk<8;kk++){
      half8 xa = *(const half8*)(xr + n16*XPITCH + kk*32 + q*8);
      xn[0] = MFMA16(xa, Ph[0][kk], xn[0]);
      xn[1] = MFMA16(xa, Ph[1][kk], xn[1]);
      xn[0] = MFMA16(xa, Pl[0][kk], xn[0]);
      xn[1] = MFMA16(xa, Pl[1][kk], xn[1]);
    }

    float* sdst = S + (size_t)(k-1)*BN;
    #pragma unroll
    for (int nt=0;nt<2;nt++)
      #pragma unroll
      for (int r=0;r<4;r++){
        float z = xn[nt][r];
        sdst[(size_t)(b0+q*4+r)*NX_ + c0+nt*16+n16] = z;
        xw[(q*4+r)*XPITCH + c0+nt*16+n16] = (_Float16)z;
      }
    block_sync_lds();
  }
}

// ---------------------------------------------------------------------------
// Phase 2: full work per chunk from correct init state.
// ---------------------------------------------------------------------------
extern "C" __global__ __launch_bounds__(512)
void phase2(const float* __restrict__ x0,
            const float* __restrict__ U,
            const float* __restrict__ Dd,
            const float* __restrict__ Wx,
            const float* __restrict__ bx,
            const float* __restrict__ Wu,
            const float* __restrict__ bu,
            const float* __restrict__ Wd,
            const float* __restrict__ bd,
            const float* __restrict__ Wy,
            const float* __restrict__ by,
            const float* __restrict__ S,
            float* __restrict__ Xout,
            float* __restrict__ Yout,
            float* __restrict__ Rout)
{
  __shared__ __align__(16) _Float16 xb[2*XBUFSZ];
  __shared__ __align__(16) _Float16 wyl[64*XPITCH];
  __shared__ __align__(16) _Float16 ub[2*UBUFH];
  __shared__ __align__(16) _Float16 db[2*DBUFH];
  __shared__ float red[64];

  const int tid  = threadIdx.x;
  const int lane = tid & 63;
  const int w    = tid >> 6;
  const int q    = lane >> 4;
  const int n16  = lane & 15;
  const int b0   = blockIdx.x * 16;
  const int ck   = blockIdx.y;
  const int t0   = ck * CHUNK;
  const int c0   = w * 32;

  const float* init = (ck==0) ? x0 : (S + (size_t)(ck-1)*B_ROWS*NX_);

  const bool isU = (tid < 256);
  const bool isD = (tid >= 256) && (tid < 384);
  const int  srow = isU ? (tid >> 4) : ((tid - 256) >> 3);
  const int  sch  = isU ? (tid & 15) : ((tid - 256) & 7);
  const float* sgbase = isU ? (U  + (size_t)(b0 + srow)*NU_ + sch*4)
                            : (Dd + (size_t)(b0 + srow)*ND_ + sch*4);
  const size_t sstep  = (size_t)B_ROWS * (isU ? NU_ : ND_);
  _Float16* sldsbase  = isU ? (ub + srow*UP + sch*4) : (db + srow*DP + sch*4);
  const int  sbufstep = isU ? UBUFH : DBUFH;

  for (int i = tid; i < 64*32; i += 512) {
    int row = i >> 5, ch = i & 31;
    const float* s = Wy + row*NX_ + ch*8;
    _Float16* dst = &wyl[row*XPITCH + ch*8];
    #pragma unroll
    for (int j=0;j<8;j++) dst[j] = (_Float16)s[j];
  }
  {
    int row = tid >> 5, ch = tid & 31;
    const float* s = init + (size_t)(b0+row)*NX_ + ch*8;
    _Float16* dst = &xb[row*XPITCH + ch*8];
    #pragma unroll
    for (int j=0;j<8;j++) dst[j] = (_Float16)s[j];
  }
  // stage U/D for t0 into buf 0
  if (isU || isD) {
    f32x4 v = *(const f32x4*)(sgbase + (size_t)t0*sstep);
    *(half4v*)sldsbase = cvt4(v);
  }

  half8 Wh[2][8], Wl[2][8];
  #pragma unroll
  for (int nt=0; nt<2; nt++) {
    const int row = c0 + nt*16 + n16;
    #pragma unroll
    for (int kk=0; kk<8; kk++) {
      const float* s = Wx + row*NX_ + kk*32 + q*8;
      half8 h, l;
      #pragma unroll
      for (int j=0;j<8;j++){
        float v = s[j];
        _Float16 hi = (_Float16)v;
        h[j] = hi;
        l[j] = (_Float16)(v - (float)hi);
      }
      Wh[nt][kk]=h; Wl[nt][kk]=l;
    }
  }
  half8 WuF[2][2];
  #pragma unroll
  for (int nt=0;nt<2;nt++){
    const int row=c0+nt*16+n16;
    #pragma unroll
    for(int kk=0;kk<2;kk++){
      const float* s=Wu+row*NU_+kk*32+q*8; half8 h;
      #pragma unroll
      for(int j=0;j<8;j++) h[j]=(_Float16)s[j];
      WuF[nt][kk]=h;
    }
  }
  half8 WdF[2];
  #pragma unroll
  for(int nt=0;nt<2;nt++){
    const int row=c0+nt*16+n16;
    const float* s=Wd+row*ND_+q*8; half8 h;
    #pragma unroll
    for(int j=0;j<8;j++) h[j]=(_Float16)s[j];
    WdF[nt]=h;
  }
  const float bxs[2] = { bx[c0+n16], bx[c0+16+n16] };
  const float bus[2] = { bu[c0+n16], bu[c0+16+n16] };
  const float bds[2] = { bd[c0+n16], bd[c0+16+n16] };
  const float bys    = (w<4) ? by[w*16+n16] : 0.f;

  float xcv[2][4];
  #pragma unroll
  for(int nt=0;nt<2;nt++)
    #pragma unroll
    for(int r=0;r<4;r++)
      xcv[nt][r] = init[(size_t)(b0+q*4+r)*NX_ + c0+nt*16+n16];

  // stats: 0 sxmin, 1 sxmax, 2 sumin, 3 sumax, 4 sdx, 5 dx_d.
  // dx_u == sumin+sumax pointwise (UX bounds == U bounds == +-1) -> folded
  // into the final sum as 2*(s2+s3).
  float st[6];
  #pragma unroll
  for(int i=0;i<6;i++) st[i]=0.f;

  block_sync_lds();

  for (int tt=0; tt<CHUNK; tt++) {
    const int t = t0 + tt;
    const int cur = tt&1;
    const _Float16* xr = xb + cur*XBUFSZ;
    _Float16*       xw = xb + (cur^1)*XBUFSZ;

    // (A) prefetch next step's U/D tile (4 regs)
    f32x4 pre;
    {
      const int tn = (tt+1 < CHUNK) ? (t+1) : t;
      if (isU || isD) pre = *(const f32x4*)(sgbase + (size_t)tn*sstep);
    }

    // (B) frag reads from staged LDS
    const _Float16* ubr = ub + cur*UBUFH;
    const _Float16* dbr = db + cur*DBUFH;
    half8 uf0 = *(const half8*)(ubr + n16*UP + q*8);
    half8 uf1 = *(const half8*)(ubr + n16*UP + 32 + q*8);
    half8 df  = *(const half8*)(dbr + n16*DP + q*8);

    f32x4 xn[2];
    xn[0] = (f32x4){bxs[0],bxs[0],bxs[0],bxs[0]};
    xn[1] = (f32x4){bxs[1],bxs[1],bxs[1],bxs[1]};
    #pragma unroll
    for (int kk=0;kk<8;kk++){
      half8 xa = *(const half8*)(xr + n16*XPITCH + kk*32 + q*8);
      xn[0] = MFMA16(xa, Wh[0][kk], xn[0]);
      xn[1] = MFMA16(xa, Wh[1][kk], xn[1]);
      xn[0] = MFMA16(xa, Wl[0][kk], xn[0]);
      xn[1] = MFMA16(xa, Wl[1][kk], xn[1]);
    }

    f32x4 fu[2], fd[2];
    fu[0] = (f32x4){bus[0],bus[0],bus[0],bus[0]};
    fu[1] = (f32x4){bus[1],bus[1],bus[1],bus[1]};
    fd[0] = (f32x4){bds[0],bds[0],bds[0],bds[0]};
    fd[1] = (f32x4){bds[1],bds[1],bds[1],bds[1]};
    fu[0] = MFMA16(uf0, WuF[0][0], fu[0]);  fu[0] = MFMA16(uf1, WuF[0][1], fu[0]);
    fu[1] = MFMA16(uf0, WuF[1][0], fu[1]);  fu[1] = MFMA16(uf1, WuF[1][1], fu[1]);
    fd[0] = MFMA16(df,  WdF[0],    fd[0]);
    fd[1] = MFMA16(df,  WdF[1],    fd[1]);

    const size_t xrowbase = (size_t)t*(B_ROWS*NX_) + (size_t)b0*NX_;
    #pragma unroll
    for (int nt=0;nt<2;nt++){
      #pragma unroll
      for (int r=0;r<4;r++){
        float f  = fu[nt][r];
        float g  = fd[nt][r];
        float z  = xn[nt][r] + f + g;
        float zc = xcv[nt][r];
        float r0 = fmaxf(-1.f - z, 0.f);
        float r1 = fmaxf( z - 1.f, 0.f);
        float r2 = fmaxf(-1.f - f, 0.f);
        float r3 = fmaxf( f - 1.f, 0.f);
        float g0 = fmaxf(-1.f - g, 0.f);
        float g1 = fmaxf( g - 1.f, 0.f);
        float dz = z - zc;
        st[0]+=r0; st[1]+=r1; st[2]+=r2; st[3]+=r3;
        st[4]+=dz*dz; st[5]+=g0+g1;
        Xout[xrowbase + (size_t)(q*4+r)*NX_ + (c0+nt*16+n16)] = z;
        xw[(q*4+r)*XPITCH + c0+nt*16+n16] = (_Float16)z;
        xcv[nt][r] = z;
      }
    }

    // (C) publish prefetched tile
    if (isU || isD) *(half4v*)(sldsbase + (cur^1)*sbufstep) = cvt4(pre);

    block_sync_lds();

    if (w < 4) {
      f32x4 ya = (f32x4){bys,bys,bys,bys};
      #pragma unroll
      for (int kk=0;kk<8;kk++){
        half8 xa = *(const half8*)(xw + n16*XPITCH + kk*32 + q*8);
        half8 wb = *(const half8*)(&wyl[(w*16+n16)*XPITCH + kk*32 + q*8]);
        ya = MFMA16(xa, wb, ya);
      }
      const size_t ybase = (size_t)t*(B_ROWS*NY_) + (size_t)b0*NY_ + w*16 + n16;
      #pragma unroll
      for (int r=0;r<4;r++)
        Yout[ybase + (size_t)(q*4+r)*NY_] = ya[r];
    }
  }

  #pragma unroll
  for (int off=32; off>=1; off>>=1){
    #pragma unroll
    for (int i=0;i<6;i++) st[i] += __shfl_down(st[i], off, 64);
  }
  __syncthreads();
  if (lane==0){
    #pragma unroll
    for (int i=0;i<6;i++) red[w*8+i] = st[i];
  }
  __syncthreads();
  if (tid==0){
    float t[6] = {0.f,0.f,0.f,0.f,0.f,0.f};
    for (int ww=0; ww<8; ww++)
      for (int i=0;i<6;i++) t[i] += red[ww*8+i];
    float s = t[0] + t[1] + 2.f*(t[2]+t[3]) + t[4] + t[5];
    atomicAdd(Rout, s * (0.2f/67108864.0f));
  }
}

extern "C" void kernel_launch(void* const* d_in, const int* in_sizes, int n_in,
                              void* d_out, int out_size, void* d_ws, size_t ws_size,
                              hipStream_t stream)
{
  const float* x0=(const float*)d_in[0];
  const float* U =(const float*)d_in[1];
  const float* Dd=(const float*)d_in[2];
  const float* Wx=(const float*)d_in[3];
  const float* bx=(const float*)d_in[4];
  const float* Wu=(const float*)d_in[5];
  const float* bu=(const float*)d_in[6];
  const float* Wd=(const float*)d_in[7];
  const float* bd=(const float*)d_in[8];
  const float* Wy=(const float*)d_in[9];
  const float* by=(const float*)d_in[10];

  float* X = (float*)d_out;
  float* Y = X + (size_t)T_STEPS*B_ROWS*NX_;
  float* R = Y + (size_t)T_STEPS*B_ROWS*NY_;

  // workspace layout (floats)
  float* B0   = (float*)d_ws;                 // 65536
  float* B1   = B0 + 65536;                   // 65536
  float* Lend = B1 + 65536;                   // 7 * 1024*256
  float* S    = Lend + (size_t)7*B_ROWS*NX_;  // 7 * 1024*256

  hipMemsetAsync(R, 0, sizeof(float), stream);

  // P = (Wx^T)^32 via repeated squaring (f32)
  matsq<<<dim3(256), dim3(256), 0, stream>>>(Wx, B1, 1);  // M^2
  matsq<<<dim3(256), dim3(256), 0, stream>>>(B1, B0, 0);  // M^4
  matsq<<<dim3(256), dim3(256), 0, stream>>>(B0, B1, 0);  // M^8
  matsq<<<dim3(256), dim3(256), 0, stream>>>(B1, B0, 0);  // M^16
  matsq<<<dim3(256), dim3(256), 0, stream>>>(B0, B1, 0);  // M^32 -> P = B1

  phase1<<<dim3(64,7), dim3(512), 0, stream>>>(x0,U,Dd,Wx,bx,Wu,bu,Wd,bd,Lend);
  combine<<<dim3(64), dim3(512), 0, stream>>>(B1, Lend, S);
  phase2<<<dim3(64,8), dim3(512), 0, stream>>>(x0,U,Dd,Wx,bx,Wu,bu,Wd,bd,Wy,by,S,X,Y,R);
}